// Round 7
// baseline (233.897 us; speedup 1.0000x reference)
//
#include <hip/hip_runtime.h>
#include <stdint.h>

typedef _Float16 h8v __attribute__((ext_vector_type(8)));
typedef _Float16 h4v __attribute__((ext_vector_type(4)));
typedef float f4v __attribute__((ext_vector_type(4)));
typedef _Float16 f16;

#define NB 8
#define CC 128
#define CB 64
#define NN 4096
#define L2E 1.4426950408889634f

#define GLD(gp, lp) __builtin_amdgcn_global_load_lds( \
    (const __attribute__((address_space(1))) void*)(gp), \
    (__attribute__((address_space(3))) void*)(lp), 16, 0, 0)

#define WAITV2() asm volatile("s_waitcnt vmcnt(2)" ::: "memory")
#define WAITV0() asm volatile("s_waitcnt vmcnt(0)" ::: "memory")
#define WAITL0() asm volatile("s_waitcnt lgkmcnt(0)" ::: "memory")

// ---------------------------------------------------------------------------
// Kernel 1: projections. R19: weight fragments loaded DIRECT from raw f32
// weights (fragment rows are 8 consecutive elements) -- pack_w deleted.
// ---------------------------------------------------------------------------
__global__ __launch_bounds__(256) void proj_kernel(
    const float* __restrict__ x, const float* __restrict__ wth,
    const float* __restrict__ wph, const float* __restrict__ wg,
    f16* __restrict__ thetaT, f16* __restrict__ phiT, f16* __restrict__ gbuf)
{
    __shared__ __align__(16) f16 xT[64][136];
    __shared__ __align__(16) f16 rep[4][16 * 72];
    const int b  = blockIdx.x & 7;
    const int n0 = (blockIdx.x >> 3) << 6;
    const int t  = threadIdx.x;

    #pragma unroll
    for (int i = 0; i < 8; i++){
        int v  = t + 256 * i;
        int c  = v >> 4;
        int j0 = (v & 15) << 2;
        const f4v xv = *(const f4v*)&x[((size_t)(b * CC + c)) * NN + n0 + j0];
        #pragma unroll
        for (int jj = 0; jj < 4; jj++) xT[j0 + jj][c] = (f16)xv[jj];
    }
    __syncthreads();

    const int w = t >> 6, lane = t & 63, quad = lane >> 4, l15 = lane & 15;
    const int rrow = lane >> 3, rcol = (lane & 7) * 8;

    h8v bx[4];
    #pragma unroll
    for (int kc = 0; kc < 4; kc++)
        bx[kc] = *(const h8v*)&xT[w * 16 + l15][kc * 32 + quad * 8];

    #pragma unroll
    for (int m3 = 0; m3 < 2; m3++){
        const float* WF = (m3 == 0) ? wth : wph;
        const float sc = (m3 == 0) ? L2E : 1.0f;   // theta pre-scaled for exp2 softmax
        f16* OUT       = (m3 == 0) ? thetaT : phiT;
        for (int ks = 0; ks < 4; ks++){
            f4v acc = {0.f, 0.f, 0.f, 0.f};
            #pragma unroll
            for (int kc = 0; kc < 4; kc++){
                const float* wr = WF + (ks * 16 + l15) * CC + kc * 32 + quad * 8;
                const f4v wa = *(const f4v*)wr;
                const f4v wb = *(const f4v*)(wr + 4);
                h8v af;
                #pragma unroll
                for (int j = 0; j < 4; j++){
                    af[j]     = (f16)(wa[j] * sc);
                    af[4 + j] = (f16)(wb[j] * sc);
                }
                acc = __builtin_amdgcn_mfma_f32_16x16x32_f16(af, bx[kc], acc, 0, 0, 0);
            }
            h4v pv;
            #pragma unroll
            for (int r = 0; r < 4; r++) pv[r] = (f16)acc[r];
            *(h4v*)&rep[w][l15 * 72 + ks * 16 + quad * 4] = pv;
        }
        #pragma unroll
        for (int j = 0; j < 2; j++){
            const h8v vv = *(const h8v*)&rep[w][(rrow + 8 * j) * 72 + rcol];
            *(h8v*)&OUT[((size_t)(b * NN + n0 + w * 16 + rrow + 8 * j)) * CB + rcol] = vv;
        }
    }

    h8v bw[4];
    #pragma unroll
    for (int kc = 0; kc < 4; kc++){
        const float* wr = wg + (w * 16 + l15) * CC + kc * 32 + quad * 8;
        const f4v wa = *(const f4v*)wr;
        const f4v wb = *(const f4v*)(wr + 4);
        #pragma unroll
        for (int j = 0; j < 4; j++){
            bw[kc][j]     = (f16)wa[j];
            bw[kc][4 + j] = (f16)wb[j];
        }
    }
    for (int ns = 0; ns < 4; ns++){
        f4v acc = {0.f, 0.f, 0.f, 0.f};
        #pragma unroll
        for (int kc = 0; kc < 4; kc++){
            const h8v af = *(const h8v*)&xT[ns * 16 + l15][kc * 32 + quad * 8];
            acc = __builtin_amdgcn_mfma_f32_16x16x32_f16(af, bw[kc], acc, 0, 0, 0);
        }
        h4v pv;
        #pragma unroll
        for (int r = 0; r < 4; r++) pv[r] = (f16)acc[r];
        *(h4v*)&rep[w][l15 * 72 + ns * 16 + quad * 4] = pv;
    }
    #pragma unroll
    for (int j = 0; j < 2; j++){
        const h8v vv = *(const h8v*)&rep[w][(rrow + 8 * j) * 72 + rcol];
        *(h8v*)&gbuf[((size_t)(b * CB + w * 16 + rrow + 8 * j)) * NN + n0 + rcol] = vv;
    }
}

// ---------------------------------------------------------------------------
// Kernel 2: fused attention + final projection + residual.
// R19: 512 threads, grid 512 (2 blk/CU, 4 waves/SIMD kept from R18), but
// 64 keys/wave/step restored: 32 macro-steps x 128 keys, h-split.
//   ph: LDS 3-deep [3][128][64] (48 KB), GLD-staged, counted vmcnt(2),
//       1 barrier/step (32 barriers vs R18's 64).
//   g:  NO LDS -- 8 direct global fragment loads at step top (L1/L2-hot),
//       consumed at PV ~600cy later; issued BEFORE staging GLDs so the
//       compiler's pre-PV wait is vmcnt(2), never draining the pipeline.
//   P:  one [16][40]/wave buffer, two 32-key sub-phases (DS in-order = safe).
//   wl loaded direct f32 in epilogue (pack_w deleted).
// ---------------------------------------------------------------------------
__global__ __launch_bounds__(512, 4) void attn_kernel(
    const f16* __restrict__ thetaT, const f16* __restrict__ phiT,
    const f16* __restrict__ gbuf, const float* __restrict__ wl,
    const float* __restrict__ x, float* __restrict__ out)
{
    __shared__ __align__(16) char SM[59392];
    f16*   const PH  = (f16*)SM;                // [3][128*64] 49152 B
    f16*   const PLD = (f16*)(SM + 49152);      // [8][16*40]  10240 B
    // epilogue overlays (staging dead):
    float* const MG  = (float*)SM;              // [4][16][68] 17408 B
    float* const ML  = (float*)(SM + 17408);    // [4][16][2]    512 B
    float* const FO  = (float*)SM;              // [128][68]   34816 B
    f16*   const YY  = (f16*)(SM + 36864);      // [64][72]     9216 B

    const int b  = blockIdx.x & 7;              // batch -> XCD swizzle
    const int q0 = (blockIdx.x >> 3) << 6;
    const int t  = threadIdx.x;
    const int w  = t >> 6;                      // 0..7
    const int lane = t & 63, quad = lane >> 4, l15 = lane & 15;
    const int wq = w & 3;                       // query group (16 q)
    const int h  = w >> 2;                      // key half of each 128-key step
    const int n0 = q0 + wq * 16;

    const size_t trow = ((size_t)(b * NN + n0 + l15)) * CB;
    const h8v a0 = *(const h8v*)&thetaT[trow + quad * 8];
    const h8v a1 = *(const h8v*)&thetaT[trow + 32 + quad * 8];

    // ph staging: thread t stages rows (t>>3), (t>>3)+64 of the 128-row tile,
    // granule t&7; source granule XOR-swizzled (both-sides rule).
    const int r0 = t >> 3;
    const int gr = (t & 7) ^ (r0 & 7);
    const f16* pS = phiT + ((size_t)(b * NN + r0)) * CB + gr * 8;
    const size_t SADV = (size_t)128 * CB;

    // read swizzle (row & 7 == l15 & 7 for all tt/h)
    const int so0 = (quad ^ (l15 & 7)) * 8;
    const int so1 = so0 ^ 32;

    // g direct-load base: row cb = l15 (+16*tt2), key = 128m + 64h + 32ks + 8quad
    const f16* pgm = gbuf + ((size_t)(b * CB + l15)) * NN + 64 * h + quad * 8;

    // prologue: stage tiles 0,1 into slots 0,1 (4 GLDs in flight)
    {
        GLD(pS,            PH + t * 8);
        GLD(pS + 64 * CB,  PH + t * 8 + 4096);
        GLD(pS + SADV,           PH + 8192 + t * 8);
        GLD(pS + SADV + 64 * CB, PH + 8192 + t * 8 + 4096);
        pS += 2 * SADV;
    }

    float mrun = -1e30f, lrun = 0.f;
    const f4v zf = {0.f, 0.f, 0.f, 0.f};
    f4v o[4];
    #pragma unroll
    for (int tt = 0; tt < 4; tt++) o[tt] = zf;

    f16* const PW = PLD + w * 640;              // wave-private P [16][40]

    int rc = 0;                                 // m % 3   (compute slot)
    int rs = 2;                                 // (m+2)%3 (stage slot)
    for (int m = 0; m < 32; m++){
        if (m < 31) WAITV2(); else WAITV0();    // ph(m) landed; never drain mid-loop
        WAITL0();
        __builtin_amdgcn_s_barrier();
        asm volatile("" ::: "memory");

        // ---- g fragment loads for THIS step (use at PV; S+softmax hides lat)
        h8v g00, g01, g02, g03, g10, g11, g12, g13;
        g00 = *(const h8v*)(pgm + (size_t)(0 * 16) * NN);
        g01 = *(const h8v*)(pgm + (size_t)(1 * 16) * NN);
        g02 = *(const h8v*)(pgm + (size_t)(2 * 16) * NN);
        g03 = *(const h8v*)(pgm + (size_t)(3 * 16) * NN);
        g10 = *(const h8v*)(pgm + (size_t)(0 * 16) * NN + 32);
        g11 = *(const h8v*)(pgm + (size_t)(1 * 16) * NN + 32);
        g12 = *(const h8v*)(pgm + (size_t)(2 * 16) * NN + 32);
        g13 = *(const h8v*)(pgm + (size_t)(3 * 16) * NN + 32);
        __builtin_amdgcn_sched_barrier(0);
        // ---- stage ph tile m+2 (AFTER g loads: pre-PV wait leaves these 2)
        if (m < 30){
            f16* d = PH + rs * 8192 + t * 8;
            GLD(pS, d);
            GLD(pS + 64 * CB, d + 4096);
            pS += SADV;
        }
        __builtin_amdgcn_sched_barrier(0);

        const f16* phc = PH + rc * 8192 + h * 64 * 64;   // this wave's 64 rows

        // ---- S^T = phi(A) * theta(B), 64 keys ----
        f4v s[4];
        __builtin_amdgcn_s_setprio(1);
        #pragma unroll
        for (int tt = 0; tt < 4; tt++){
            const f16* pr = phc + (tt * 16 + l15) * 64;
            const h8v pb0 = *(const h8v*)(pr + so0);
            const h8v pb1 = *(const h8v*)(pr + so1);
            f4v sv = zf;
            sv = __builtin_amdgcn_mfma_f32_16x16x32_f16(pb0, a0, sv, 0, 0, 0);
            sv = __builtin_amdgcn_mfma_f32_16x16x32_f16(pb1, a1, sv, 0, 0, 0);
            s[tt] = sv;
        }
        __builtin_amdgcn_s_setprio(0);

        // ---- online softmax, defer-max (log2 domain; lane owns query l15) ----
        float smax = fmaxf(fmaxf(s[0][0], s[0][1]), fmaxf(s[0][2], s[0][3]));
        #pragma unroll
        for (int tt = 1; tt < 4; tt++)
            smax = fmaxf(smax, fmaxf(fmaxf(s[tt][0], s[tt][1]), fmaxf(s[tt][2], s[tt][3])));
        smax = fmaxf(smax, __shfl_xor(smax, 16));
        smax = fmaxf(smax, __shfl_xor(smax, 32));

        if (__any(smax - mrun > 8.f)){
            const float mn = fmaxf(mrun, smax);
            const float alpha = __builtin_amdgcn_exp2f(mrun - mn);
            mrun = mn;
            lrun *= alpha;
            #pragma unroll
            for (int tt = 0; tt < 4; tt++)
                #pragma unroll
                for (int r = 0; r < 4; r++)
                    o[tt][r] *= alpha;
        }

        float lsum = 0.f;
        h4v pvh0, pvh1;                         // tt=2,3 held for sub-phase 1
        #pragma unroll
        for (int tt = 0; tt < 4; tt++){
            h4v pv;
            #pragma unroll
            for (int r = 0; r < 4; r++){
                float p = __builtin_amdgcn_exp2f(s[tt][r] - mrun);
                lsum += p;
                pv[r] = (f16)p;
            }
            if (tt == 0)      *(h4v*)&PW[l15 * 40 +      quad * 4] = pv;
            else if (tt == 1) *(h4v*)&PW[l15 * 40 + 16 + quad * 4] = pv;
            else if (tt == 2) pvh0 = pv;
            else              pvh1 = pv;
        }
        lrun += lsum;

        // ---- PV sub-phase 0 (keys 0..31 of tile) ----
        const h8v pa0 = *(const h8v*)&PW[l15 * 40 + quad * 8];
        __builtin_amdgcn_s_setprio(1);
        o[0] = __builtin_amdgcn_mfma_f32_16x16x32_f16(g00, pa0, o[0], 0, 0, 0);
        o[1] = __builtin_amdgcn_mfma_f32_16x16x32_f16(g01, pa0, o[1], 0, 0, 0);
        o[2] = __builtin_amdgcn_mfma_f32_16x16x32_f16(g02, pa0, o[2], 0, 0, 0);
        o[3] = __builtin_amdgcn_mfma_f32_16x16x32_f16(g03, pa0, o[3], 0, 0, 0);
        __builtin_amdgcn_s_setprio(0);

        // ---- PV sub-phase 1 (keys 32..63; reuse PW -- DS in-order per wave)
        *(h4v*)&PW[l15 * 40 +      quad * 4] = pvh0;
        *(h4v*)&PW[l15 * 40 + 16 + quad * 4] = pvh1;
        const h8v pa1 = *(const h8v*)&PW[l15 * 40 + quad * 8];
        __builtin_amdgcn_s_setprio(1);
        o[0] = __builtin_amdgcn_mfma_f32_16x16x32_f16(g10, pa1, o[0], 0, 0, 0);
        o[1] = __builtin_amdgcn_mfma_f32_16x16x32_f16(g11, pa1, o[1], 0, 0, 0);
        o[2] = __builtin_amdgcn_mfma_f32_16x16x32_f16(g12, pa1, o[2], 0, 0, 0);
        o[3] = __builtin_amdgcn_mfma_f32_16x16x32_f16(g13, pa1, o[3], 0, 0, 0);
        __builtin_amdgcn_s_setprio(0);

        pgm += 128;
        rc = (rc == 2) ? 0 : rc + 1;
        rs = (rs == 2) ? 0 : rs + 1;
    }

    // per-wave l reduce across quads (full l for this wave's key half)
    lrun += __shfl_xor(lrun, 16);
    lrun += __shfl_xor(lrun, 32);

    __syncthreads();   // K-loop done; staging region dead -> merge overlay

    if (h == 1){       // odd-half waves publish (m, l, O)
        #pragma unroll
        for (int tt2 = 0; tt2 < 4; tt2++)
            *(f4v*)&MG[wq * 1088 + l15 * 68 + tt2 * 16 + quad * 4] = o[tt2];
        if (lane < 16){
            ML[wq * 32 + lane * 2 + 0] = mrun;
            ML[wq * 32 + lane * 2 + 1] = lrun;
        }
    }
    __syncthreads();

    if (h == 0){       // even-half waves merge + normalize -> y (f16)
        const float m4 = ML[wq * 32 + l15 * 2 + 0];
        const float l4 = ML[wq * 32 + l15 * 2 + 1];
        const float M  = fmaxf(mrun, m4);
        const float e0 = __builtin_amdgcn_exp2f(mrun - M);
        const float e1 = __builtin_amdgcn_exp2f(m4 - M);
        const float inv = 1.0f / (lrun * e0 + l4 * e1);
        #pragma unroll
        for (int tt2 = 0; tt2 < 4; tt2++){
            const f4v o4 = *(const f4v*)&MG[wq * 1088 + l15 * 68 + tt2 * 16 + quad * 4];
            h4v yv;
            #pragma unroll
            for (int r = 0; r < 4; r++)
                yv[r] = (f16)((o[tt2][r] * e0 + o4[r] * e1) * inv);
            *(h4v*)&YY[(wq * 16 + l15) * 72 + tt2 * 16 + quad * 4] = yv;
        }
    }
    __syncthreads();

    // ---- out-GEMM: D[c][q] = wl(A) * y(B); wl fragments loaded direct f32 ----
    const h8v yB0 = *(const h8v*)&YY[(wq * 16 + l15) * 72 + quad * 8];
    const h8v yB1 = *(const h8v*)&YY[(wq * 16 + l15) * 72 + 32 + quad * 8];
    #pragma unroll
    for (int ci = 0; ci < 4; ci++){
        const int cs = h * 4 + ci;
        const float* wrow = wl + (cs * 16 + l15) * CB + quad * 8;
        const f4v wA0 = *(const f4v*)(wrow);
        const f4v wA1 = *(const f4v*)(wrow + 4);
        const f4v wB0 = *(const f4v*)(wrow + 32);
        const f4v wB1 = *(const f4v*)(wrow + 36);
        h8v wa0, wa1;
        #pragma unroll
        for (int j = 0; j < 4; j++){
            wa0[j]     = (f16)wA0[j];
            wa0[4 + j] = (f16)wA1[j];
            wa1[j]     = (f16)wB0[j];
            wa1[4 + j] = (f16)wB1[j];
        }
        f4v acc = zf;
        acc = __builtin_amdgcn_mfma_f32_16x16x32_f16(wa0, yB0, acc, 0, 0, 0);
        acc = __builtin_amdgcn_mfma_f32_16x16x32_f16(wa1, yB1, acc, 0, 0, 0);
        #pragma unroll
        for (int r = 0; r < 4; r++)
            FO[(cs * 16 + quad * 4 + r) * 68 + wq * 16 + l15] = acc[r];
    }
    __syncthreads();

    // ---- residual RMW: fully coalesced float4, 512 threads ----
    #pragma unroll
    for (int i = 0; i < 4; i++){
        const int row = i * 32 + (t >> 4);
        const int nf  = (t & 15) * 4;
        const f4v v = *(const f4v*)&FO[row * 68 + nf];
        const size_t idx = ((size_t)(b * CC + row)) * NN + q0 + nf;
        const f4v xv = *(const f4v*)&x[idx];
        f4v ov;
        #pragma unroll
        for (int r = 0; r < 4; r++) ov[r] = v[r] + xv[r];
        *(f4v*)&out[idx] = ov;
    }
}

extern "C" void kernel_launch(void* const* d_in, const int* in_sizes, int n_in,
                              void* d_out, int out_size, void* d_ws, size_t ws_size,
                              hipStream_t stream)
{
    const float* x   = (const float*)d_in[0];
    const float* wth = (const float*)d_in[1];
    const float* wph = (const float*)d_in[2];
    const float* wg  = (const float*)d_in[3];
    const float* wl  = (const float*)d_in[4];
    float* out = (float*)d_out;

    f16* thetaT = (f16*)d_ws;
    f16* phiT   = thetaT + (size_t)NB * NN * CB;
    f16* gbuf   = phiT   + (size_t)NB * NN * CB;

    proj_kernel<<<NB * 64, 256, 0, stream>>>(x, wth, wph, wg, thetaT, phiT, gbuf);
    attn_kernel<<<NB * 64, 512, 0, stream>>>(thetaT, phiT, gbuf, wl, x, out);
}

// Round 8
// 178.488 us; speedup vs baseline: 1.3104x; 1.3104x over previous
//
#include <hip/hip_runtime.h>
#include <stdint.h>

typedef _Float16 h8v __attribute__((ext_vector_type(8)));
typedef _Float16 h4v __attribute__((ext_vector_type(4)));
typedef float f4v __attribute__((ext_vector_type(4)));
typedef _Float16 f16;

#define NB 8
#define CC 128
#define CB 64
#define NN 4096
#define L2E 1.4426950408889634f

#define GLD(gp, lp) __builtin_amdgcn_global_load_lds( \
    (const __attribute__((address_space(1))) void*)(gp), \
    (__attribute__((address_space(3))) void*)(lp), 16, 0, 0)

#define WAITV2() asm volatile("s_waitcnt vmcnt(2)" ::: "memory")
#define WAITV0() asm volatile("s_waitcnt vmcnt(0)" ::: "memory")
#define WAITL0() asm volatile("s_waitcnt lgkmcnt(0)" ::: "memory")

// ---------------------------------------------------------------------------
// Kernel 0: pack weights into f16 MFMA-fragment order (once per launch).
// wth pre-scaled by log2(e) for attn's exp2 softmax.
// ---------------------------------------------------------------------------
__global__ __launch_bounds__(256) void pack_w(
    const float* __restrict__ wth, const float* __restrict__ wph,
    const float* __restrict__ wg,  const float* __restrict__ wl,
    f16* __restrict__ wthp, f16* __restrict__ wphp,
    f16* __restrict__ wgp,  f16* __restrict__ wlp)
{
    const int t = blockIdx.x * 256 + threadIdx.x;      // 2048 threads
    for (int i = t; i < 8192; i += 2048){
        const int j = i & 7, lane = (i >> 3) & 63, kc = (i >> 9) & 3, ks = i >> 11;
        const int row = ks * 16 + (lane & 15);
        const int col = kc * 32 + ((lane >> 4) & 3) * 8 + j;
        wthp[i] = (f16)(wth[row * CC + col] * L2E);
        wphp[i] = (f16)(wph[row * CC + col]);
        wgp [i] = (f16)(wg [row * CC + col]);
    }
    for (int i = t; i < 8192; i += 2048){
        const int j = i & 7, lane = (i >> 3) & 63, kc = (i >> 9) & 1, cs = i >> 10;
        const int row = cs * 16 + (lane & 15);
        const int col = kc * 32 + ((lane >> 4) & 3) * 8 + j;
        wlp[i] = (f16)(wl[row * CB + col]);
    }
}

// ---------------------------------------------------------------------------
// Kernel 1: projections (R18 version, proven).
// ---------------------------------------------------------------------------
__global__ __launch_bounds__(256) void proj_kernel(
    const float* __restrict__ x, const f16* __restrict__ wthp,
    const f16* __restrict__ wphp, const f16* __restrict__ wgp,
    f16* __restrict__ thetaT, f16* __restrict__ phiT, f16* __restrict__ gbuf)
{
    __shared__ __align__(16) f16 xT[64][136];
    __shared__ __align__(16) f16 rep[4][16 * 72];
    const int b  = blockIdx.x & 7;
    const int n0 = (blockIdx.x >> 3) << 6;
    const int t  = threadIdx.x;

    #pragma unroll
    for (int i = 0; i < 8; i++){
        int v  = t + 256 * i;
        int c  = v >> 4;
        int j0 = (v & 15) << 2;
        const f4v xv = *(const f4v*)&x[((size_t)(b * CC + c)) * NN + n0 + j0];
        #pragma unroll
        for (int jj = 0; jj < 4; jj++) xT[j0 + jj][c] = (f16)xv[jj];
    }
    __syncthreads();

    const int w = t >> 6, lane = t & 63, quad = lane >> 4, l15 = lane & 15;
    const int rrow = lane >> 3, rcol = (lane & 7) * 8;

    h8v bx[4];
    #pragma unroll
    for (int kc = 0; kc < 4; kc++)
        bx[kc] = *(const h8v*)&xT[w * 16 + l15][kc * 32 + quad * 8];

    #pragma unroll
    for (int m3 = 0; m3 < 2; m3++){
        const f16* WP = (m3 == 0) ? wthp : wphp;
        f16* OUT      = (m3 == 0) ? thetaT : phiT;
        for (int ks = 0; ks < 4; ks++){
            f4v acc = {0.f, 0.f, 0.f, 0.f};
            #pragma unroll
            for (int kc = 0; kc < 4; kc++){
                const h8v af = *(const h8v*)&WP[(ks * 4 + kc) * 512 + lane * 8];
                acc = __builtin_amdgcn_mfma_f32_16x16x32_f16(af, bx[kc], acc, 0, 0, 0);
            }
            h4v pv;
            #pragma unroll
            for (int r = 0; r < 4; r++) pv[r] = (f16)acc[r];
            *(h4v*)&rep[w][l15 * 72 + ks * 16 + quad * 4] = pv;
        }
        #pragma unroll
        for (int j = 0; j < 2; j++){
            const h8v vv = *(const h8v*)&rep[w][(rrow + 8 * j) * 72 + rcol];
            *(h8v*)&OUT[((size_t)(b * NN + n0 + w * 16 + rrow + 8 * j)) * CB + rcol] = vv;
        }
    }

    h8v bw[4];
    #pragma unroll
    for (int kc = 0; kc < 4; kc++)
        bw[kc] = *(const h8v*)&wgp[(w * 4 + kc) * 512 + lane * 8];
    for (int ns = 0; ns < 4; ns++){
        f4v acc = {0.f, 0.f, 0.f, 0.f};
        #pragma unroll
        for (int kc = 0; kc < 4; kc++){
            const h8v af = *(const h8v*)&xT[ns * 16 + l15][kc * 32 + quad * 8];
            acc = __builtin_amdgcn_mfma_f32_16x16x32_f16(af, bw[kc], acc, 0, 0, 0);
        }
        h4v pv;
        #pragma unroll
        for (int r = 0; r < 4; r++) pv[r] = (f16)acc[r];
        *(h4v*)&rep[w][l15 * 72 + ns * 16 + quad * 4] = pv;
    }
    #pragma unroll
    for (int j = 0; j < 2; j++){
        const h8v vv = *(const h8v*)&rep[w][(rrow + 8 * j) * 72 + rcol];
        *(h8v*)&gbuf[((size_t)(b * CB + w * 16 + rrow + 8 * j)) * NN + n0 + rcol] = vv;
    }
}

// ---------------------------------------------------------------------------
// Kernel 2: fused attention + final projection + residual.
// R20 = R18 exact structure (512 thr, 8 waves, h-split 32-key tiles, 3-deep
// pair staging, counted vmcnt(2), raw barriers, defer-max, setprio) with ONE
// change: P-IN-REGISTER PV via key permutation. MFMA's K dim is a formal
// index: with sigma(Q,j) = 4Q+(j&3)+16(j>>2) applied to BOTH operands, the
// B-fragment equals the lane's own exp2 outputs (pa[j] = exp(s[j>>2][j&3]))
// -- no cross-lane movement, no P LDS round-trip -- and the A-side absorbs
// sigma by reading two b64 granules (c = Q>>1 and 2|(Q>>1), stored position
// c ^ (row&3), sub-offset (Q&1)*4) from the already-swizzled GG tile.
// PLD deleted: LDS 59392 -> 49152.
// ---------------------------------------------------------------------------
__global__ __launch_bounds__(512, 4) void attn_kernel(
    const f16* __restrict__ thetaT, const f16* __restrict__ phiT,
    const f16* __restrict__ gbuf, const f16* __restrict__ wlp,
    const float* __restrict__ x, float* __restrict__ out)
{
    __shared__ __align__(16) char SM[49152];
    f16*   const PH  = (f16*)SM;                // [6][32*64]  24576 B
    f16*   const GG  = (f16*)(SM + 24576);      // [6][64*32]  24576 B
    // epilogue overlays (staging dead):
    float* const MG  = (float*)SM;              // [4][16][68] 17408 B
    float* const ML  = (float*)(SM + 17408);    // [4][16][2]    512 B
    float* const FO  = (float*)SM;              // [128][68]   34816 B
    f16*   const YY  = (f16*)(SM + 36864);      // [64][72]     9216 B

    const int b  = blockIdx.x & 7;              // batch -> XCD swizzle
    const int q0 = (blockIdx.x >> 3) << 6;
    const int t  = threadIdx.x;
    const int w  = t >> 6;                      // 0..7
    const int lane = t & 63, quad = lane >> 4, l15 = lane & 15;
    const int wq = w & 3;                       // query group
    const int h  = w >> 2;                      // key half (even/odd tiles)
    const int n0 = q0 + wq * 16;

    // theta fragments (16 queries per wave)
    const size_t trow = ((size_t)(b * NN + n0 + l15)) * CB;
    const h8v a0 = *(const h8v*)&thetaT[trow + quad * 8];
    const h8v a1 = *(const h8v*)&thetaT[trow + 32 + quad * 8];

    // ---- staging assignment: 16 x 1KB segments/step, 2 per wave ----
    const int seg  = w * 2;
    const int tsel = seg >> 3;
    const int kind = (seg >> 2) & 1;
    const int qa   = seg & 3;                   // 0 or 2 (wave-uniform)
    const f16* sA;  const f16* sB;  size_t adv;
    if (kind == 0){                             // ph tile [key32][cb64]
        const int row = qa * 8 + (lane >> 3);
        const int gr  = (lane & 7) ^ (lane >> 3);        // XOR-swz source
        sA = phiT + ((size_t)(b * NN + tsel * 32 + row)) * CB + gr * 8;
        sB = sA + (size_t)8 * CB;
        adv = (size_t)64 * CB;                  // +2 tiles per step
    } else {                                    // g tile [cb64][key32]
        const int row = qa * 16 + (lane >> 2);
        const int gr  = (lane & 3) ^ ((lane >> 2) & 3);
        sA = gbuf + ((size_t)(b * CB + row)) * NN + tsel * 32 + gr * 8;
        sB = sA + (size_t)16 * NN;
        adv = 64;
    }
    f16* const dBase = (kind == 0) ? PH : GG;
    const int dOff = qa * 512;                  // f16 units (wave-uniform)

    // swizzled read offsets
    const int so0 = (quad ^ (l15 & 7)) * 8;     // ph: cb granule quad
    const int so1 = so0 ^ 32;                   //     cb granule quad+4
    // g permuted-key b64 offsets: logical granule c stored at c ^ (row&3)
    const int g_off0 = (((quad >> 1)    ) ^ (l15 & 3)) * 8 + (quad & 1) * 4;
    const int g_off1 = (((quad >> 1) | 2) ^ (l15 & 3)) * 8 + (quad & 1) * 4;

    // prologue: stage tile pairs 0 (slots tsel) and 1 (slots 2+tsel)
    {
        f16* d0 = dBase + (0 + tsel) * 2048 + dOff;
        GLD(sA, d0);  GLD(sB, d0 + 512);
        f16* d1 = dBase + (2 + tsel) * 2048 + dOff;
        GLD(sA + adv, d1);  GLD(sB + adv, d1 + 512);
    }
    const f16* pA = sA + 2 * adv;
    const f16* pB = sB + 2 * adv;

    float mrun = -1e30f, lrun = 0.f;
    const f4v zf = {0.f, 0.f, 0.f, 0.f};
    f4v o[4];
    #pragma unroll
    for (int tt = 0; tt < 4; tt++) o[tt] = zf;

    int rc = 0;                                 // m % 3   (compute slot pair)
    int rs = 2;                                 // (m+2)%3 (stage slot pair)
    for (int m = 0; m < 64; m++){
        if (m < 63) WAITV2(); else WAITV0();    // pair m landed; never drain
        WAITL0();
        __builtin_amdgcn_s_barrier();
        asm volatile("" ::: "memory");
        if (m < 62){                            // stage pair m+2
            f16* d = dBase + (2 * rs + tsel) * 2048 + dOff;
            GLD(pA, d);  GLD(pB, d + 512);
            pA += adv;   pB += adv;
        }
        const int ct = 2 * rc + h;              // this wave's tile slot
        const f16* phc = PH + ct * 2048;
        const f16* ggc = GG + ct * 2048;

        // ---- S^T = phi(A) * theta(B), 32 keys ----
        f4v s[2];
        __builtin_amdgcn_s_setprio(1);
        #pragma unroll
        for (int tt = 0; tt < 2; tt++){
            const f16* pr = phc + (tt * 16 + l15) * 64;
            const h8v pb0 = *(const h8v*)(pr + so0);
            const h8v pb1 = *(const h8v*)(pr + so1);
            f4v sv = zf;
            sv = __builtin_amdgcn_mfma_f32_16x16x32_f16(pb0, a0, sv, 0, 0, 0);
            sv = __builtin_amdgcn_mfma_f32_16x16x32_f16(pb1, a1, sv, 0, 0, 0);
            s[tt] = sv;
        }
        __builtin_amdgcn_s_setprio(0);

        // ---- online softmax, defer-max (log2 domain; lane owns query l15) ----
        float smax = fmaxf(fmaxf(s[0][0], s[0][1]), fmaxf(s[0][2], s[0][3]));
        smax = fmaxf(smax, fmaxf(fmaxf(s[1][0], s[1][1]), fmaxf(s[1][2], s[1][3])));
        smax = fmaxf(smax, __shfl_xor(smax, 16));
        smax = fmaxf(smax, __shfl_xor(smax, 32));

        if (__any(smax - mrun > 8.f)){
            const float mn = fmaxf(mrun, smax);
            const float alpha = __builtin_amdgcn_exp2f(mrun - mn);
            mrun = mn;
            lrun *= alpha;
            #pragma unroll
            for (int tt = 0; tt < 4; tt++)
                #pragma unroll
                for (int r = 0; r < 4; r++)
                    o[tt][r] *= alpha;
        }

        // ---- P stays in registers: pa[j] = exp(s[j>>2][j&3]) ----
        float lsum = 0.f;
        h8v pa;
        #pragma unroll
        for (int tt = 0; tt < 2; tt++)
            #pragma unroll
            for (int r = 0; r < 4; r++){
                float p = __builtin_amdgcn_exp2f(s[tt][r] - mrun);
                lsum += p;
                pa[tt * 4 + r] = (f16)p;
            }
        lrun += lsum;

        // ---- O^T += g(A) * P(B), keys permuted by sigma on BOTH sides ----
        __builtin_amdgcn_s_setprio(1);
        #pragma unroll
        for (int tt2 = 0; tt2 < 4; tt2++){
            const f16* grow = ggc + (tt2 * 16 + l15) * 32;
            const h4v ga = *(const h4v*)(grow + g_off0);
            const h4v gb = *(const h4v*)(grow + g_off1);
            h8v g8;
            #pragma unroll
            for (int j = 0; j < 4; j++){ g8[j] = ga[j]; g8[4 + j] = gb[j]; }
            o[tt2] = __builtin_amdgcn_mfma_f32_16x16x32_f16(g8, pa, o[tt2], 0, 0, 0);
        }
        __builtin_amdgcn_s_setprio(0);

        rc = (rc == 2) ? 0 : rc + 1;
        rs = (rs == 2) ? 0 : rs + 1;
    }

    // per-wave l reduce across quads (full l for this wave's key half)
    lrun += __shfl_xor(lrun, 16);
    lrun += __shfl_xor(lrun, 32);

    __syncthreads();   // K-loop done; staging region dead -> merge overlay

    if (h == 1){       // odd-half waves publish (m, l, O)
        #pragma unroll
        for (int tt2 = 0; tt2 < 4; tt2++)
            *(f4v*)&MG[wq * 1088 + l15 * 68 + tt2 * 16 + quad * 4] = o[tt2];
        if (lane < 16){
            ML[wq * 32 + lane * 2 + 0] = mrun;
            ML[wq * 32 + lane * 2 + 1] = lrun;
        }
    }
    __syncthreads();

    if (h == 0){       // even-half waves merge + normalize -> y (f16)
        const float m4 = ML[wq * 32 + l15 * 2 + 0];
        const float l4 = ML[wq * 32 + l15 * 2 + 1];
        const float M  = fmaxf(mrun, m4);
        const float e0 = __builtin_amdgcn_exp2f(mrun - M);
        const float e1 = __builtin_amdgcn_exp2f(m4 - M);
        const float inv = 1.0f / (lrun * e0 + l4 * e1);
        #pragma unroll
        for (int tt2 = 0; tt2 < 4; tt2++){
            const f4v o4 = *(const f4v*)&MG[wq * 1088 + l15 * 68 + tt2 * 16 + quad * 4];
            h4v yv;
            #pragma unroll
            for (int r = 0; r < 4; r++)
                yv[r] = (f16)((o[tt2][r] * e0 + o4[r] * e1) * inv);
            *(h4v*)&YY[(wq * 16 + l15) * 72 + tt2 * 16 + quad * 4] = yv;
        }
    }
    __syncthreads();

    // ---- out-GEMM: D[c][q] = wl(A) * y(B); 8 waves, 4 cs each ----
    const h8v yB0 = *(const h8v*)&YY[(wq * 16 + l15) * 72 + quad * 8];
    const h8v yB1 = *(const h8v*)&YY[(wq * 16 + l15) * 72 + 32 + quad * 8];
    #pragma unroll
    for (int ci = 0; ci < 4; ci++){
        const int cs = h * 4 + ci;
        const h8v wa0 = *(const h8v*)&wlp[(cs * 2 + 0) * 512 + lane * 8];
        const h8v wa1 = *(const h8v*)&wlp[(cs * 2 + 1) * 512 + lane * 8];
        f4v acc = zf;
        acc = __builtin_amdgcn_mfma_f32_16x16x32_f16(wa0, yB0, acc, 0, 0, 0);
        acc = __builtin_amdgcn_mfma_f32_16x16x32_f16(wa1, yB1, acc, 0, 0, 0);
        #pragma unroll
        for (int r = 0; r < 4; r++)
            FO[(cs * 16 + quad * 4 + r) * 68 + wq * 16 + l15] = acc[r];
    }
    __syncthreads();

    // ---- residual RMW: fully coalesced float4, 512 threads ----
    #pragma unroll
    for (int i = 0; i < 4; i++){
        const int row = i * 32 + (t >> 4);
        const int nf  = (t & 15) * 4;
        const f4v v = *(const f4v*)&FO[row * 68 + nf];
        const size_t idx = ((size_t)(b * CC + row)) * NN + q0 + nf;
        const f4v xv = *(const f4v*)&x[idx];
        f4v ov;
        #pragma unroll
        for (int r = 0; r < 4; r++) ov[r] = v[r] + xv[r];
        *(f4v*)&out[idx] = ov;
    }
}

extern "C" void kernel_launch(void* const* d_in, const int* in_sizes, int n_in,
                              void* d_out, int out_size, void* d_ws, size_t ws_size,
                              hipStream_t stream)
{
    const float* x   = (const float*)d_in[0];
    const float* wth = (const float*)d_in[1];
    const float* wph = (const float*)d_in[2];
    const float* wg  = (const float*)d_in[3];
    const float* wl  = (const float*)d_in[4];
    float* out = (float*)d_out;

    f16* thetaT = (f16*)d_ws;
    f16* phiT   = thetaT + (size_t)NB * NN * CB;
    f16* gbuf   = phiT   + (size_t)NB * NN * CB;
    f16* wthp   = gbuf   + (size_t)NB * NN * CB;
    f16* wphp   = wthp + 8192;
    f16* wgp    = wphp + 8192;
    f16* wlp    = wgp  + 8192;

    pack_w<<<8, 256, 0, stream>>>(wth, wph, wg, wl, wthp, wphp, wgp, wlp);
    proj_kernel<<<NB * 64, 256, 0, stream>>>(x, wthp, wphp, wgp, thetaT, phiT, gbuf);
    attn_kernel<<<NB * 64, 512, 0, stream>>>(thetaT, phiT, gbuf, wlp, x, out);
}

// Round 10
// 145.818 us; speedup vs baseline: 1.6040x; 1.2240x over previous
//
#include <hip/hip_runtime.h>
#include <stdint.h>

typedef _Float16 h8v __attribute__((ext_vector_type(8)));
typedef _Float16 h4v __attribute__((ext_vector_type(4)));
typedef float f4v __attribute__((ext_vector_type(4)));
typedef _Float16 f16;

#define NB 8
#define CC 128
#define CB 64
#define NN 4096
#define L2E 1.4426950408889634f

#define GLD(gp, lp) __builtin_amdgcn_global_load_lds( \
    (const __attribute__((address_space(1))) void*)(gp), \
    (__attribute__((address_space(3))) void*)(lp), 16, 0, 0)

#define WAITV1() asm volatile("s_waitcnt vmcnt(1)" ::: "memory")
#define WAITV0() asm volatile("s_waitcnt vmcnt(0)" ::: "memory")
#define WAITL0() asm volatile("s_waitcnt lgkmcnt(0)" ::: "memory")

// ---------------------------------------------------------------------------
// Kernel 0: pack weights into f16 MFMA-fragment order (once per launch).
// wth pre-scaled by log2(e) for attn's exp2 softmax.
// ---------------------------------------------------------------------------
__global__ __launch_bounds__(256) void pack_w(
    const float* __restrict__ wth, const float* __restrict__ wph,
    const float* __restrict__ wg,  const float* __restrict__ wl,
    f16* __restrict__ wthp, f16* __restrict__ wphp,
    f16* __restrict__ wgp,  f16* __restrict__ wlp)
{
    const int t = blockIdx.x * 256 + threadIdx.x;      // 2048 threads
    for (int i = t; i < 8192; i += 2048){
        const int j = i & 7, lane = (i >> 3) & 63, kc = (i >> 9) & 3, ks = i >> 11;
        const int row = ks * 16 + (lane & 15);
        const int col = kc * 32 + ((lane >> 4) & 3) * 8 + j;
        wthp[i] = (f16)(wth[row * CC + col] * L2E);
        wphp[i] = (f16)(wph[row * CC + col]);
        wgp [i] = (f16)(wg [row * CC + col]);
    }
    for (int i = t; i < 8192; i += 2048){
        const int j = i & 7, lane = (i >> 3) & 63, kc = (i >> 9) & 1, cs = i >> 10;
        const int row = cs * 16 + (lane & 15);
        const int col = kc * 32 + ((lane >> 4) & 3) * 8 + j;
        wlp[i] = (f16)(wl[row * CB + col]);
    }
}

// ---------------------------------------------------------------------------
// Kernel 1: projections (R18 version, proven).
// ---------------------------------------------------------------------------
__global__ __launch_bounds__(256) void proj_kernel(
    const float* __restrict__ x, const f16* __restrict__ wthp,
    const f16* __restrict__ wphp, const f16* __restrict__ wgp,
    f16* __restrict__ thetaT, f16* __restrict__ phiT, f16* __restrict__ gbuf)
{
    __shared__ __align__(16) f16 xT[64][136];
    __shared__ __align__(16) f16 rep[4][16 * 72];
    const int b  = blockIdx.x & 7;
    const int n0 = (blockIdx.x >> 3) << 6;
    const int t  = threadIdx.x;

    #pragma unroll
    for (int i = 0; i < 8; i++){
        int v  = t + 256 * i;
        int c  = v >> 4;
        int j0 = (v & 15) << 2;
        const f4v xv = *(const f4v*)&x[((size_t)(b * CC + c)) * NN + n0 + j0];
        #pragma unroll
        for (int jj = 0; jj < 4; jj++) xT[j0 + jj][c] = (f16)xv[jj];
    }
    __syncthreads();

    const int w = t >> 6, lane = t & 63, quad = lane >> 4, l15 = lane & 15;
    const int rrow = lane >> 3, rcol = (lane & 7) * 8;

    h8v bx[4];
    #pragma unroll
    for (int kc = 0; kc < 4; kc++)
        bx[kc] = *(const h8v*)&xT[w * 16 + l15][kc * 32 + quad * 8];

    #pragma unroll
    for (int m3 = 0; m3 < 2; m3++){
        const f16* WP = (m3 == 0) ? wthp : wphp;
        f16* OUT      = (m3 == 0) ? thetaT : phiT;
        for (int ks = 0; ks < 4; ks++){
            f4v acc = {0.f, 0.f, 0.f, 0.f};
            #pragma unroll
            for (int kc = 0; kc < 4; kc++){
                const h8v af = *(const h8v*)&WP[(ks * 4 + kc) * 512 + lane * 8];
                acc = __builtin_amdgcn_mfma_f32_16x16x32_f16(af, bx[kc], acc, 0, 0, 0);
            }
            h4v pv;
            #pragma unroll
            for (int r = 0; r < 4; r++) pv[r] = (f16)acc[r];
            *(h4v*)&rep[w][l15 * 72 + ks * 16 + quad * 4] = pv;
        }
        #pragma unroll
        for (int j = 0; j < 2; j++){
            const h8v vv = *(const h8v*)&rep[w][(rrow + 8 * j) * 72 + rcol];
            *(h8v*)&OUT[((size_t)(b * NN + n0 + w * 16 + rrow + 8 * j)) * CB + rcol] = vv;
        }
    }

    h8v bw[4];
    #pragma unroll
    for (int kc = 0; kc < 4; kc++)
        bw[kc] = *(const h8v*)&wgp[(w * 4 + kc) * 512 + lane * 8];
    for (int ns = 0; ns < 4; ns++){
        f4v acc = {0.f, 0.f, 0.f, 0.f};
        #pragma unroll
        for (int kc = 0; kc < 4; kc++){
            const h8v af = *(const h8v*)&xT[ns * 16 + l15][kc * 32 + quad * 8];
            acc = __builtin_amdgcn_mfma_f32_16x16x32_f16(af, bw[kc], acc, 0, 0, 0);
        }
        h4v pv;
        #pragma unroll
        for (int r = 0; r < 4; r++) pv[r] = (f16)acc[r];
        *(h4v*)&rep[w][l15 * 72 + ns * 16 + quad * 4] = pv;
    }
    #pragma unroll
    for (int j = 0; j < 2; j++){
        const h8v vv = *(const h8v*)&rep[w][(rrow + 8 * j) * 72 + rcol];
        *(h8v*)&gbuf[((size_t)(b * CB + w * 16 + rrow + 8 * j)) * NN + n0 + rcol] = vv;
    }
}

// ---------------------------------------------------------------------------
// Kernel 2: fused attention + final projection + residual.
// R22 = R21 with the staging-advance fix (pS += 64*CB, pG += 64 per STEP --
// R21 advanced TWO pairs per step, staging wrong tiles -> absmax 6.77).
// Structure: P-in-register sigma permutation (R20-verified) + GG stored
// PRE-PERMUTED via reg-staged g (T14) so PV reads ONE conflict-free b128:
//   stored: key k -> tile (k>>5), chunk ((k>>2)&3) ^ ((row>>1)&3),
//           pos (k&3) + 4*((k&31)>=16)
//   read:   b128 at chunk quad ^ ((l15>>1)&3) == keys {4q+r, 16+4q+r}
//           == R20's verified g8 fragment; pa[j]=exp2(s[j>>2][j&3]).
// Staging: 512 thr x (1 GLD ph + 1 load g + 2 ds_write_b64)/64-key pair,
// 3-deep pair slots, top-of-step vmcnt(1) (ph GLD rides across barrier, T4),
// ping-pong g reg sets via 2x-unrolled STEP (static indexing, rule 20).
// ---------------------------------------------------------------------------
__global__ __launch_bounds__(512, 4) void attn_kernel(
    const f16* __restrict__ thetaT, const f16* __restrict__ phiT,
    const f16* __restrict__ gbuf, const f16* __restrict__ wlp,
    const float* __restrict__ x, float* __restrict__ out)
{
    __shared__ __align__(16) char SM[49152];
    f16*   const PH  = (f16*)SM;                // [3][4096]   24576 B
    f16*   const GG  = (f16*)(SM + 24576);      // [3][4096]   24576 B
    // epilogue overlays (staging dead):
    float* const MG  = (float*)SM;              // [4][16][68] 17408 B
    float* const ML  = (float*)(SM + 17408);    // [4][16][2]    512 B
    float* const FO  = (float*)SM;              // [128][68]   34816 B
    f16*   const YY  = (f16*)(SM + 36864);      // [64][72]     9216 B

    const int b  = blockIdx.x & 7;              // batch -> XCD swizzle
    const int q0 = (blockIdx.x >> 3) << 6;
    const int t  = threadIdx.x;
    const int w  = t >> 6;                      // 0..7
    const int lane = t & 63, quad = lane >> 4, l15 = lane & 15;
    const int wq = w & 3;                       // query group
    const int h  = w >> 2;                      // key half of 64-key pair
    const int n0 = q0 + wq * 16;

    // theta fragments (16 queries per wave)
    const size_t trow = ((size_t)(b * NN + n0 + l15)) * CB;
    const h8v a0 = *(const h8v*)&thetaT[trow + quad * 8];
    const h8v a1 = *(const h8v*)&thetaT[trow + 32 + quad * 8];

    // ---- staging (all 512 threads; srow = key/cb row 0..63 of the pair) ----
    const int srow = t >> 3;
    const int skg  = t & 7;
    const f16* pS = phiT + ((size_t)(b * NN + srow)) * CB + (skg ^ (srow & 7)) * 8;
    const f16* pG = gbuf + ((size_t)(b * CB + srow)) * NN + skg * 8;
    // g sigma-store: this thread's 8 keys = skg*8..+7 -> 2 chunks x 4 f16
    const int sgs = (srow >> 1) & 3;
    const int cA  = (2 * (skg & 3)) & 3;
    const int gdA = (skg >> 2) * 2048 + srow * 32 + ((cA      ^ sgs) * 8) + ((skg >> 1) & 1) * 4;
    const int gdB = (skg >> 2) * 2048 + srow * 32 + (((cA | 1) ^ sgs) * 8) + ((skg >> 1) & 1) * 4;

    // read offsets
    const int so0 = (quad ^ (l15 & 7)) * 8;           // ph b128 chunk
    const int so1 = so0 ^ 32;
    const int gvs = (quad ^ ((l15 >> 1) & 3)) * 8;    // GG sigma b128 chunk

    // ---- prologue: g pairs 0,1 -> regs; ph pairs 0,1 -> slots 0,1 ----
    h8v gA = *(const h8v*)pG;                   // g pair 0
    h8v gB = *(const h8v*)(pG + 64);            // g pair 1
    GLD(pS,                    PH + t * 8);
    GLD(pS + (size_t)64 * CB,  PH + 4096 + t * 8);
    pG += 128;                                  // -> pair 2
    pS += (size_t)128 * CB;                     // -> pair 2
    {   // write g pair 0 -> slot 0 (compiler inserts counted vmcnt for gA)
        h4v lo, hi;
        #pragma unroll
        for (int j = 0; j < 4; j++){ lo[j] = gA[j]; hi[j] = gA[4 + j]; }
        *(h4v*)&GG[gdA] = lo;
        *(h4v*)&GG[gdB] = hi;
    }

    float mrun = -1e30f, lrun = 0.f;
    const f4v zf = {0.f, 0.f, 0.f, 0.f};
    f4v o[4];
    #pragma unroll
    for (int tt = 0; tt < 4; tt++) o[tt] = zf;

    int rc = 0;                                 // compute pair-slot m%3

    // STEP(m): write g(m+1) from gw -> slot (m+1)%3; load g(m+2) -> gl;
    //          GLD ph(m+2) -> slot (m+2)%3; compute pair m.
    auto STEP = [&](int m, h8v& gw, h8v& gl){
        if (m < 63) WAITV1(); else WAITV0();    // ph(m),g(m+1) landed; ph(m+1) rides
        WAITL0();
        __builtin_amdgcn_s_barrier();
        asm volatile("" ::: "memory");

        if (m < 63){
            const int wsl = (rc == 2) ? 0 : rc + 1;
            h4v lo, hi;
            #pragma unroll
            for (int j = 0; j < 4; j++){ lo[j] = gw[j]; hi[j] = gw[4 + j]; }
            *(h4v*)&GG[wsl * 4096 + gdA] = lo;
            *(h4v*)&GG[wsl * 4096 + gdB] = hi;
        }
        if (m < 62){
            gl = *(const h8v*)pG;  pG += 64;    // ONE pair per step (R21 fix)
            __builtin_amdgcn_sched_barrier(0);  // keep g-load older than ph GLD
            const int gsl = (rc == 0) ? 2 : rc - 1;
            GLD(pS, PH + gsl * 4096 + t * 8);
            pS += (size_t)64 * CB;              // ONE pair per step (R21 fix)
        }

        const f16* phc = PH + rc * 4096 + h * 2048;
        const f16* ggc = GG + rc * 4096 + h * 2048;

        // ---- S^T = phi(A) * theta(B), 32 keys ----
        f4v s[2];
        __builtin_amdgcn_s_setprio(1);
        #pragma unroll
        for (int tt = 0; tt < 2; tt++){
            const f16* pr = phc + (tt * 16 + l15) * 64;
            const h8v pb0 = *(const h8v*)(pr + so0);
            const h8v pb1 = *(const h8v*)(pr + so1);
            f4v sv = zf;
            sv = __builtin_amdgcn_mfma_f32_16x16x32_f16(pb0, a0, sv, 0, 0, 0);
            sv = __builtin_amdgcn_mfma_f32_16x16x32_f16(pb1, a1, sv, 0, 0, 0);
            s[tt] = sv;
        }
        __builtin_amdgcn_s_setprio(0);

        // ---- online softmax, defer-max (log2 domain; lane owns query l15) ----
        float smax = fmaxf(fmaxf(s[0][0], s[0][1]), fmaxf(s[0][2], s[0][3]));
        smax = fmaxf(smax, fmaxf(fmaxf(s[1][0], s[1][1]), fmaxf(s[1][2], s[1][3])));
        smax = fmaxf(smax, __shfl_xor(smax, 16));
        smax = fmaxf(smax, __shfl_xor(smax, 32));

        if (__any(smax - mrun > 8.f)){
            const float mn = fmaxf(mrun, smax);
            const float alpha = __builtin_amdgcn_exp2f(mrun - mn);
            mrun = mn;
            lrun *= alpha;
            #pragma unroll
            for (int tt = 0; tt < 4; tt++)
                #pragma unroll
                for (int r = 0; r < 4; r++)
                    o[tt][r] *= alpha;
        }

        // ---- P in registers: pa[j] = exp2(s[j>>2][j&3] - mrun) ----
        float lsum = 0.f;
        h8v pa;
        #pragma unroll
        for (int tt = 0; tt < 2; tt++)
            #pragma unroll
            for (int r = 0; r < 4; r++){
                float p = __builtin_amdgcn_exp2f(s[tt][r] - mrun);
                lsum += p;
                pa[tt * 4 + r] = (f16)p;
            }
        lrun += lsum;

        // ---- O^T += g(A) * P(B); GG pre-permuted -> one b128 each ----
        __builtin_amdgcn_s_setprio(1);
        #pragma unroll
        for (int tt2 = 0; tt2 < 4; tt2++){
            const h8v g8 = *(const h8v*)(ggc + (tt2 * 16 + l15) * 32 + gvs);
            o[tt2] = __builtin_amdgcn_mfma_f32_16x16x32_f16(g8, pa, o[tt2], 0, 0, 0);
        }
        __builtin_amdgcn_s_setprio(0);

        rc = (rc == 2) ? 0 : rc + 1;
    };

    for (int mm = 0; mm < 64; mm += 2){
        STEP(mm,     gB, gA);                   // write g(mm+1)=gB, load g(mm+2)->gA
        STEP(mm + 1, gA, gB);                   // write g(mm+2)=gA, load g(mm+3)->gB
    }

    // per-wave l reduce across quads (full l for this wave's key half)
    lrun += __shfl_xor(lrun, 16);
    lrun += __shfl_xor(lrun, 32);

    __syncthreads();   // K-loop done; staging region dead -> merge overlay

    if (h == 1){       // odd-half waves publish (m, l, O)
        #pragma unroll
        for (int tt2 = 0; tt2 < 4; tt2++)
            *(f4v*)&MG[wq * 1088 + l15 * 68 + tt2 * 16 + quad * 4] = o[tt2];
        if (lane < 16){
            ML[wq * 32 + lane * 2 + 0] = mrun;
            ML[wq * 32 + lane * 2 + 1] = lrun;
        }
    }
    __syncthreads();

    if (h == 0){       // even-half waves merge + normalize -> y (f16)
        const float m4 = ML[wq * 32 + l15 * 2 + 0];
        const float l4 = ML[wq * 32 + l15 * 2 + 1];
        const float M  = fmaxf(mrun, m4);
        const float e0 = __builtin_amdgcn_exp2f(mrun - M);
        const float e1 = __builtin_amdgcn_exp2f(m4 - M);
        const float inv = 1.0f / (lrun * e0 + l4 * e1);
        #pragma unroll
        for (int tt2 = 0; tt2 < 4; tt2++){
            const f4v o4 = *(const f4v*)&MG[wq * 1088 + l15 * 68 + tt2 * 16 + quad * 4];
            h4v yv;
            #pragma unroll
            for (int r = 0; r < 4; r++)
                yv[r] = (f16)((o[tt2][r] * e0 + o4[r] * e1) * inv);
            *(h4v*)&YY[(wq * 16 + l15) * 72 + tt2 * 16 + quad * 4] = yv;
        }
    }
    __syncthreads();

    // ---- out-GEMM: D[c][q] = wl(A) * y(B); 8 waves, 4 cs each ----
    const h8v yB0 = *(const h8v*)&YY[(wq * 16 + l15) * 72 + quad * 8];
    const h8v yB1 = *(const h8v*)&YY[(wq * 16 + l15) * 72 + 32 + quad * 8];
    #pragma unroll
    for (int ci = 0; ci < 4; ci++){
        const int cs = h * 4 + ci;
        const h8v wa0 = *(const h8v*)&wlp[(cs * 2 + 0) * 512 + lane * 8];
        const h8v wa1 = *(const h8v*)&wlp[(cs * 2 + 1) * 512 + lane * 8];
        f4v acc = zf;
        acc = __builtin_amdgcn_mfma_f32_16x16x32_f16(wa0, yB0, acc, 0, 0, 0);
        acc = __builtin_amdgcn_mfma_f32_16x16x32_f16(wa1, yB1, acc, 0, 0, 0);
        #pragma unroll
        for (int r = 0; r < 4; r++)
            FO[(cs * 16 + quad * 4 + r) * 68 + wq * 16 + l15] = acc[r];
    }
    __syncthreads();

    // ---- residual RMW: fully coalesced float4, 512 threads ----
    #pragma unroll
    for (int i = 0; i < 4; i++){
        const int row = i * 32 + (t >> 4);
        const int nf  = (t & 15) * 4;
        const f4v v = *(const f4v*)&FO[row * 68 + nf];
        const size_t idx = ((size_t)(b * CC + row)) * NN + q0 + nf;
        const f4v xv = *(const f4v*)&x[idx];
        f4v ov;
        #pragma unroll
        for (int r = 0; r < 4; r++) ov[r] = v[r] + xv[r];
        *(f4v*)&out[idx] = ov;
    }
}

extern "C" void kernel_launch(void* const* d_in, const int* in_sizes, int n_in,
                              void* d_out, int out_size, void* d_ws, size_t ws_size,
                              hipStream_t stream)
{
    const float* x   = (const float*)d_in[0];
    const float* wth = (const float*)d_in[1];
    const float* wph = (const float*)d_in[2];
    const float* wg  = (const float*)d_in[3];
    const float* wl  = (const float*)d_in[4];
    float* out = (float*)d_out;

    f16* thetaT = (f16*)d_ws;
    f16* phiT   = thetaT + (size_t)NB * NN * CB;
    f16* gbuf   = phiT   + (size_t)NB * NN * CB;
    f16* wthp   = gbuf   + (size_t)NB * NN * CB;
    f16* wphp   = wthp + 8192;
    f16* wgp    = wphp + 8192;
    f16* wlp    = wgp  + 8192;

    pack_w<<<8, 256, 0, stream>>>(wth, wph, wg, wl, wthp, wphp, wgp, wlp);
    proj_kernel<<<NB * 64, 256, 0, stream>>>(x, wthp, wphp, wgp, thetaT, phiT, gbuf);
    attn_kernel<<<NB * 64, 512, 0, stream>>>(thetaT, phiT, gbuf, wlp, x, out);
}

// Round 11
// 143.713 us; speedup vs baseline: 1.6275x; 1.0147x over previous
//
#include <hip/hip_runtime.h>
#include <stdint.h>

typedef _Float16 h8v __attribute__((ext_vector_type(8)));
typedef _Float16 h4v __attribute__((ext_vector_type(4)));
typedef float f4v __attribute__((ext_vector_type(4)));
typedef _Float16 f16;

#define NB 8
#define CC 128
#define CB 64
#define NN 4096
#define L2E 1.4426950408889634f

#define GLD(gp, lp) __builtin_amdgcn_global_load_lds( \
    (const __attribute__((address_space(1))) void*)(gp), \
    (__attribute__((address_space(3))) void*)(lp), 16, 0, 0)

#define WAITV1() asm volatile("s_waitcnt vmcnt(1)" ::: "memory")
#define WAITV0() asm volatile("s_waitcnt vmcnt(0)" ::: "memory")
#define WAITL0() asm volatile("s_waitcnt lgkmcnt(0)" ::: "memory")

// ---------------------------------------------------------------------------
// Kernel 0: pack weights into f16 MFMA-fragment order (once per launch).
// wth pre-scaled by log2(e) for attn's exp2 softmax.
// ---------------------------------------------------------------------------
__global__ __launch_bounds__(256) void pack_w(
    const float* __restrict__ wth, const float* __restrict__ wph,
    const float* __restrict__ wg,  const float* __restrict__ wl,
    f16* __restrict__ wthp, f16* __restrict__ wphp,
    f16* __restrict__ wgp,  f16* __restrict__ wlp)
{
    const int t = blockIdx.x * 256 + threadIdx.x;      // 2048 threads
    for (int i = t; i < 8192; i += 2048){
        const int j = i & 7, lane = (i >> 3) & 63, kc = (i >> 9) & 3, ks = i >> 11;
        const int row = ks * 16 + (lane & 15);
        const int col = kc * 32 + ((lane >> 4) & 3) * 8 + j;
        wthp[i] = (f16)(wth[row * CC + col] * L2E);
        wphp[i] = (f16)(wph[row * CC + col]);
        wgp [i] = (f16)(wg [row * CC + col]);
    }
    for (int i = t; i < 8192; i += 2048){
        const int j = i & 7, lane = (i >> 3) & 63, kc = (i >> 9) & 1, cs = i >> 10;
        const int row = cs * 16 + (lane & 15);
        const int col = kc * 32 + ((lane >> 4) & 3) * 8 + j;
        wlp[i] = (f16)(wl[row * CB + col]);
    }
}

// ---------------------------------------------------------------------------
// Kernel 1: projections (R18 version, proven).
// ---------------------------------------------------------------------------
__global__ __launch_bounds__(256) void proj_kernel(
    const float* __restrict__ x, const f16* __restrict__ wthp,
    const f16* __restrict__ wphp, const f16* __restrict__ wgp,
    f16* __restrict__ thetaT, f16* __restrict__ phiT, f16* __restrict__ gbuf)
{
    __shared__ __align__(16) f16 xT[64][136];
    __shared__ __align__(16) f16 rep[4][16 * 72];
    const int b  = blockIdx.x & 7;
    const int n0 = (blockIdx.x >> 3) << 6;
    const int t  = threadIdx.x;

    #pragma unroll
    for (int i = 0; i < 8; i++){
        int v  = t + 256 * i;
        int c  = v >> 4;
        int j0 = (v & 15) << 2;
        const f4v xv = *(const f4v*)&x[((size_t)(b * CC + c)) * NN + n0 + j0];
        #pragma unroll
        for (int jj = 0; jj < 4; jj++) xT[j0 + jj][c] = (f16)xv[jj];
    }
    __syncthreads();

    const int w = t >> 6, lane = t & 63, quad = lane >> 4, l15 = lane & 15;
    const int rrow = lane >> 3, rcol = (lane & 7) * 8;

    h8v bx[4];
    #pragma unroll
    for (int kc = 0; kc < 4; kc++)
        bx[kc] = *(const h8v*)&xT[w * 16 + l15][kc * 32 + quad * 8];

    #pragma unroll
    for (int m3 = 0; m3 < 2; m3++){
        const f16* WP = (m3 == 0) ? wthp : wphp;
        f16* OUT      = (m3 == 0) ? thetaT : phiT;
        for (int ks = 0; ks < 4; ks++){
            f4v acc = {0.f, 0.f, 0.f, 0.f};
            #pragma unroll
            for (int kc = 0; kc < 4; kc++){
                const h8v af = *(const h8v*)&WP[(ks * 4 + kc) * 512 + lane * 8];
                acc = __builtin_amdgcn_mfma_f32_16x16x32_f16(af, bx[kc], acc, 0, 0, 0);
            }
            h4v pv;
            #pragma unroll
            for (int r = 0; r < 4; r++) pv[r] = (f16)acc[r];
            *(h4v*)&rep[w][l15 * 72 + ks * 16 + quad * 4] = pv;
        }
        #pragma unroll
        for (int j = 0; j < 2; j++){
            const h8v vv = *(const h8v*)&rep[w][(rrow + 8 * j) * 72 + rcol];
            *(h8v*)&OUT[((size_t)(b * NN + n0 + w * 16 + rrow + 8 * j)) * CB + rcol] = vv;
        }
    }

    h8v bw[4];
    #pragma unroll
    for (int kc = 0; kc < 4; kc++)
        bw[kc] = *(const h8v*)&wgp[(w * 4 + kc) * 512 + lane * 8];
    for (int ns = 0; ns < 4; ns++){
        f4v acc = {0.f, 0.f, 0.f, 0.f};
        #pragma unroll
        for (int kc = 0; kc < 4; kc++){
            const h8v af = *(const h8v*)&xT[ns * 16 + l15][kc * 32 + quad * 8];
            acc = __builtin_amdgcn_mfma_f32_16x16x32_f16(af, bw[kc], acc, 0, 0, 0);
        }
        h4v pv;
        #pragma unroll
        for (int r = 0; r < 4; r++) pv[r] = (f16)acc[r];
        *(h4v*)&rep[w][l15 * 72 + ns * 16 + quad * 4] = pv;
    }
    #pragma unroll
    for (int j = 0; j < 2; j++){
        const h8v vv = *(const h8v*)&rep[w][(rrow + 8 * j) * 72 + rcol];
        *(h8v*)&gbuf[((size_t)(b * CB + w * 16 + rrow + 8 * j)) * NN + n0 + rcol] = vv;
    }
}

// ---------------------------------------------------------------------------
// Kernel 2: fused attention + final projection + residual.
// R23 = R22 (P-in-register sigma PV, pre-permuted GG via reg-staged g,
// 3-deep gl_lds ph, counted vmcnt(1), raw barriers) with VALU cuts:
//   - STEPK(RC,...) macro, 6x-unrolled (lcm of 3-slot rotation, 2-reg
//     ping-pong): all LDS addresses = 6 base regs + compile-time offsets;
//     modular slot selects eliminated.
//   - defer-max check WITHOUT cross-quad shuffles on the common path:
//     __any(partial_max > thr) fires iff __any(full_max > thr); the
//     quad-reduction moves inside the rare rescale branch.
// Schedule/ledger byte-identical to R22.
// ---------------------------------------------------------------------------
__global__ __launch_bounds__(512, 4) void attn_kernel(
    const f16* __restrict__ thetaT, const f16* __restrict__ phiT,
    const f16* __restrict__ gbuf, const f16* __restrict__ wlp,
    const float* __restrict__ x, float* __restrict__ out)
{
    __shared__ __align__(16) char SM[49152];
    f16*   const PH  = (f16*)SM;                // [3][4096]   24576 B
    f16*   const GG  = (f16*)(SM + 24576);      // [3][4096]   24576 B
    // epilogue overlays (staging dead):
    float* const MG  = (float*)SM;              // [4][16][68] 17408 B
    float* const ML  = (float*)(SM + 17408);    // [4][16][2]    512 B
    float* const FO  = (float*)SM;              // [128][68]   34816 B
    f16*   const YY  = (f16*)(SM + 36864);      // [64][72]     9216 B

    const int b  = blockIdx.x & 7;              // batch -> XCD swizzle
    const int q0 = (blockIdx.x >> 3) << 6;
    const int t  = threadIdx.x;
    const int w  = t >> 6;                      // 0..7
    const int lane = t & 63, quad = lane >> 4, l15 = lane & 15;
    const int wq = w & 3;                       // query group
    const int h  = w >> 2;                      // key half of 64-key pair
    const int n0 = q0 + wq * 16;

    // theta fragments (16 queries per wave)
    const size_t trow = ((size_t)(b * NN + n0 + l15)) * CB;
    const h8v a0 = *(const h8v*)&thetaT[trow + quad * 8];
    const h8v a1 = *(const h8v*)&thetaT[trow + 32 + quad * 8];

    // ---- staging (all 512 threads; srow = key/cb row 0..63 of the pair) ----
    const int srow = t >> 3;
    const int skg  = t & 7;
    const f16* pS = phiT + ((size_t)(b * NN + srow)) * CB + (skg ^ (srow & 7)) * 8;
    const f16* pG = gbuf + ((size_t)(b * CB + srow)) * NN + skg * 8;
    // g sigma-store: this thread's 8 keys = skg*8..+7 -> 2 chunks x 4 f16
    const int sgs = (srow >> 1) & 3;
    const int cA  = (2 * (skg & 3)) & 3;
    const int gdA = (skg >> 2) * 2048 + srow * 32 + ((cA      ^ sgs) * 8) + ((skg >> 1) & 1) * 4;
    const int gdB = (skg >> 2) * 2048 + srow * 32 + (((cA | 1) ^ sgs) * 8) + ((skg >> 1) & 1) * 4;

    // read swizzles
    const int so0 = (quad ^ (l15 & 7)) * 8;           // ph b128 chunk
    const int so1 = so0 ^ 32;
    const int gvs = (quad ^ ((l15 >> 1) & 3)) * 8;    // GG sigma b128 chunk

    // precomputed base pointers; all slot/tt selects become imm offsets
    const f16* const PB0 = PH + h * 2048 + l15 * 64 + so0;
    const f16* const PB1 = PH + h * 2048 + l15 * 64 + so1;
    const f16* const GB  = GG + h * 2048 + l15 * 32 + gvs;
    f16* const WA = GG + gdA;
    f16* const WB = GG + gdB;
    f16* const PD = PH + t * 8;

    // ---- prologue: g pairs 0,1 -> regs; ph pairs 0,1 -> slots 0,1 ----
    h8v gA = *(const h8v*)pG;                   // g pair 0
    h8v gB = *(const h8v*)(pG + 64);            // g pair 1
    GLD(pS,                    PD);
    GLD(pS + (size_t)64 * CB,  PD + 4096);
    pG += 128;                                  // -> pair 2
    pS += (size_t)128 * CB;                     // -> pair 2
    {   // write g pair 0 -> slot 0
        h4v lo_, hi_;
        #pragma unroll
        for (int j = 0; j < 4; j++){ lo_[j] = gA[j]; hi_[j] = gA[4 + j]; }
        *(h4v*)&WA[0] = lo_;
        *(h4v*)&WB[0] = hi_;
    }

    float mrun = -1e30f, lrun = 0.f;
    const f4v zf = {0.f, 0.f, 0.f, 0.f};
    f4v o[4];
    #pragma unroll
    for (int tt = 0; tt < 4; tt++) o[tt] = zf;

// STEPK(RC, V1, DO_W, DO_L, gw, gl): compute pair with slot RC (literal);
// write g-next from gw into slot (RC+1)%3; load g(m+2)->gl; GLD ph(m+2)
// into slot (RC+2)%3. vmcnt ledger identical to R22.
#define STEPK(RC, V1, DO_W, DO_L, gw, gl) do {                              \
    if (V1) WAITV1(); else WAITV0();                                        \
    WAITL0();                                                               \
    __builtin_amdgcn_s_barrier();                                           \
    asm volatile("" ::: "memory");                                          \
    if (DO_W){                                                              \
        h4v lo_, hi_;                                                       \
        _Pragma("unroll")                                                   \
        for (int j = 0; j < 4; j++){ lo_[j] = gw[j]; hi_[j] = gw[4 + j]; }  \
        *(h4v*)&WA[((RC + 1) % 3) * 4096] = lo_;                            \
        *(h4v*)&WB[((RC + 1) % 3) * 4096] = hi_;                            \
    }                                                                       \
    if (DO_L){                                                              \
        gl = *(const h8v*)pG;  pG += 64;                                    \
        __builtin_amdgcn_sched_barrier(0);                                  \
        GLD(pS, PD + ((RC + 2) % 3) * 4096);                                \
        pS += (size_t)64 * CB;                                              \
    }                                                                       \
    f4v s0_, s1_;                                                           \
    __builtin_amdgcn_s_setprio(1);                                          \
    {                                                                       \
        const h8v pb0 = *(const h8v*)(PB0 + RC * 4096);                     \
        const h8v pb1 = *(const h8v*)(PB1 + RC * 4096);                     \
        f4v sv = zf;                                                        \
        sv = __builtin_amdgcn_mfma_f32_16x16x32_f16(pb0, a0, sv, 0, 0, 0);  \
        sv = __builtin_amdgcn_mfma_f32_16x16x32_f16(pb1, a1, sv, 0, 0, 0);  \
        s0_ = sv;                                                           \
        const h8v pb2 = *(const h8v*)(PB0 + RC * 4096 + 1024);              \
        const h8v pb3 = *(const h8v*)(PB1 + RC * 4096 + 1024);              \
        f4v sw = zf;                                                        \
        sw = __builtin_amdgcn_mfma_f32_16x16x32_f16(pb2, a0, sw, 0, 0, 0);  \
        sw = __builtin_amdgcn_mfma_f32_16x16x32_f16(pb3, a1, sw, 0, 0, 0);  \
        s1_ = sw;                                                           \
    }                                                                       \
    __builtin_amdgcn_s_setprio(0);                                          \
    float smax_ = fmaxf(fmaxf(s0_[0], s0_[1]), fmaxf(s0_[2], s0_[3]));      \
    smax_ = fmaxf(smax_, fmaxf(fmaxf(s1_[0], s1_[1]), fmaxf(s1_[2], s1_[3])));\
    if (__any(smax_ - mrun > 8.f)){                                         \
        smax_ = fmaxf(smax_, __shfl_xor(smax_, 16));                        \
        smax_ = fmaxf(smax_, __shfl_xor(smax_, 32));                        \
        const float mn_ = fmaxf(mrun, smax_);                               \
        const float al_ = __builtin_amdgcn_exp2f(mrun - mn_);               \
        mrun = mn_;                                                         \
        lrun *= al_;                                                        \
        _Pragma("unroll")                                                   \
        for (int tt = 0; tt < 4; tt++)                                      \
            _Pragma("unroll")                                               \
            for (int r = 0; r < 4; r++)                                     \
                o[tt][r] *= al_;                                            \
    }                                                                       \
    float lsum_ = 0.f;                                                      \
    h8v pa_;                                                                \
    _Pragma("unroll")                                                       \
    for (int r = 0; r < 4; r++){                                            \
        float p_ = __builtin_amdgcn_exp2f(s0_[r] - mrun);                   \
        lsum_ += p_;  pa_[r] = (f16)p_;                                     \
        float q_ = __builtin_amdgcn_exp2f(s1_[r] - mrun);                   \
        lsum_ += q_;  pa_[4 + r] = (f16)q_;                                 \
    }                                                                       \
    lrun += lsum_;                                                          \
    __builtin_amdgcn_s_setprio(1);                                          \
    o[0] = __builtin_amdgcn_mfma_f32_16x16x32_f16(                          \
        *(const h8v*)(GB + RC * 4096 +    0), pa_, o[0], 0, 0, 0);          \
    o[1] = __builtin_amdgcn_mfma_f32_16x16x32_f16(                          \
        *(const h8v*)(GB + RC * 4096 +  512), pa_, o[1], 0, 0, 0);          \
    o[2] = __builtin_amdgcn_mfma_f32_16x16x32_f16(                          \
        *(const h8v*)(GB + RC * 4096 + 1024), pa_, o[2], 0, 0, 0);          \
    o[3] = __builtin_amdgcn_mfma_f32_16x16x32_f16(                          \
        *(const h8v*)(GB + RC * 4096 + 1536), pa_, o[3], 0, 0, 0);          \
    __builtin_amdgcn_s_setprio(0);                                          \
} while (0)

    // m = 0..59 (all full steps): 10 x 6-unrolled
    for (int mm = 0; mm < 60; mm += 6){
        STEPK(0, 1, 1, 1, gB, gA);
        STEPK(1, 1, 1, 1, gA, gB);
        STEPK(2, 1, 1, 1, gB, gA);
        STEPK(0, 1, 1, 1, gA, gB);
        STEPK(1, 1, 1, 1, gB, gA);
        STEPK(2, 1, 1, 1, gA, gB);
    }
    STEPK(0, 1, 1, 1, gB, gA);   // m=60: stage pair 62 -> gA
    STEPK(1, 1, 1, 1, gA, gB);   // m=61: stage pair 63 -> gB
    STEPK(2, 1, 1, 0, gB, gA);   // m=62: write g(63)=gB, no loads
    STEPK(0, 0, 0, 0, gA, gB);   // m=63: drain, compute only
#undef STEPK

    // per-wave l reduce across quads (full l for this wave's key half)
    lrun += __shfl_xor(lrun, 16);
    lrun += __shfl_xor(lrun, 32);

    __syncthreads();   // K-loop done; staging region dead -> merge overlay

    if (h == 1){       // odd-half waves publish (m, l, O)
        #pragma unroll
        for (int tt2 = 0; tt2 < 4; tt2++)
            *(f4v*)&MG[wq * 1088 + l15 * 68 + tt2 * 16 + quad * 4] = o[tt2];
        if (lane < 16){
            ML[wq * 32 + lane * 2 + 0] = mrun;
            ML[wq * 32 + lane * 2 + 1] = lrun;
        }
    }
    __syncthreads();

    if (h == 0){       // even-half waves merge + normalize -> y (f16)
        const float m4 = ML[wq * 32 + l15 * 2 + 0];
        const float l4 = ML[wq * 32 + l15 * 2 + 1];
        const float M  = fmaxf(mrun, m4);
        const float e0 = __builtin_amdgcn_exp2f(mrun - M);
        const float e1 = __builtin_amdgcn_exp2f(m4 - M);
        const float inv = 1.0f / (lrun * e0 + l4 * e1);
        #pragma unroll
        for (int tt2 = 0; tt2 < 4; tt2++){
            const f4v o4 = *(const f4v*)&MG[wq * 1088 + l15 * 68 + tt2 * 16 + quad * 4];
            h4v yv;
            #pragma unroll
            for (int r = 0; r < 4; r++)
                yv[r] = (f16)((o[tt2][r] * e0 + o4[r] * e1) * inv);
            *(h4v*)&YY[(wq * 16 + l15) * 72 + tt2 * 16 + quad * 4] = yv;
        }
    }
    __syncthreads();

    // ---- out-GEMM: D[c][q] = wl(A) * y(B); 8 waves, 4 cs each ----
    const f4v zf2 = {0.f, 0.f, 0.f, 0.f};
    const h8v yB0 = *(const h8v*)&YY[(wq * 16 + l15) * 72 + quad * 8];
    const h8v yB1 = *(const h8v*)&YY[(wq * 16 + l15) * 72 + 32 + quad * 8];
    #pragma unroll
    for (int ci = 0; ci < 4; ci++){
        const int cs = h * 4 + ci;
        const h8v wa0 = *(const h8v*)&wlp[(cs * 2 + 0) * 512 + lane * 8];
        const h8v wa1 = *(const h8v*)&wlp[(cs * 2 + 1) * 512 + lane * 8];
        f4v acc = zf2;
        acc = __builtin_amdgcn_mfma_f32_16x16x32_f16(wa0, yB0, acc, 0, 0, 0);
        acc = __builtin_amdgcn_mfma_f32_16x16x32_f16(wa1, yB1, acc, 0, 0, 0);
        #pragma unroll
        for (int r = 0; r < 4; r++)
            FO[(cs * 16 + quad * 4 + r) * 68 + wq * 16 + l15] = acc[r];
    }
    __syncthreads();

    // ---- residual RMW: fully coalesced float4, 512 threads ----
    #pragma unroll
    for (int i = 0; i < 4; i++){
        const int row = i * 32 + (t >> 4);
        const int nf  = (t & 15) * 4;
        const f4v v = *(const f4v*)&FO[row * 68 + nf];
        const size_t idx = ((size_t)(b * CC + row)) * NN + q0 + nf;
        const f4v xv = *(const f4v*)&x[idx];
        f4v ov;
        #pragma unroll
        for (int r = 0; r < 4; r++) ov[r] = v[r] + xv[r];
        *(f4v*)&out[idx] = ov;
    }
}

extern "C" void kernel_launch(void* const* d_in, const int* in_sizes, int n_in,
                              void* d_out, int out_size, void* d_ws, size_t ws_size,
                              hipStream_t stream)
{
    const float* x   = (const float*)d_in[0];
    const float* wth = (const float*)d_in[1];
    const float* wph = (const float*)d_in[2];
    const float* wg  = (const float*)d_in[3];
    const float* wl  = (const float*)d_in[4];
    float* out = (float*)d_out;

    f16* thetaT = (f16*)d_ws;
    f16* phiT   = thetaT + (size_t)NB * NN * CB;
    f16* gbuf   = phiT   + (size_t)NB * NN * CB;
    f16* wthp   = gbuf   + (size_t)NB * NN * CB;
    f16* wphp   = wthp + 8192;
    f16* wgp    = wphp + 8192;
    f16* wlp    = wgp  + 8192;

    pack_w<<<8, 256, 0, stream>>>(wth, wph, wg, wl, wthp, wphp, wgp, wlp);
    proj_kernel<<<NB * 64, 256, 0, stream>>>(x, wthp, wphp, wgp, thetaT, phiT, gbuf);
    attn_kernel<<<NB * 64, 512, 0, stream>>>(thetaT, phiT, gbuf, wlp, x, out);
}

// Round 12
// 139.555 us; speedup vs baseline: 1.6760x; 1.0298x over previous
//
#include <hip/hip_runtime.h>
#include <stdint.h>

typedef _Float16 h8v __attribute__((ext_vector_type(8)));
typedef _Float16 h4v __attribute__((ext_vector_type(4)));
typedef float f4v __attribute__((ext_vector_type(4)));
typedef _Float16 f16;

#define NB 8
#define CC 128
#define CB 64
#define NN 4096
#define L2E 1.4426950408889634f

#define GLD(gp, lp) __builtin_amdgcn_global_load_lds( \
    (const __attribute__((address_space(1))) void*)(gp), \
    (__attribute__((address_space(3))) void*)(lp), 16, 0, 0)

#define WAITV1() asm volatile("s_waitcnt vmcnt(1)" ::: "memory")
#define WAITV0() asm volatile("s_waitcnt vmcnt(0)" ::: "memory")
#define WAITL0() asm volatile("s_waitcnt lgkmcnt(0)" ::: "memory")

// ---------------------------------------------------------------------------
// Kernel 0: pack weights into f16 MFMA-fragment order (once per launch).
// wth pre-scaled by log2(e) for attn's exp2 softmax.
// ---------------------------------------------------------------------------
__global__ __launch_bounds__(256) void pack_w(
    const float* __restrict__ wth, const float* __restrict__ wph,
    const float* __restrict__ wg,  const float* __restrict__ wl,
    f16* __restrict__ wthp, f16* __restrict__ wphp,
    f16* __restrict__ wgp,  f16* __restrict__ wlp)
{
    const int t = blockIdx.x * 256 + threadIdx.x;      // 2048 threads
    for (int i = t; i < 8192; i += 2048){
        const int j = i & 7, lane = (i >> 3) & 63, kc = (i >> 9) & 3, ks = i >> 11;
        const int row = ks * 16 + (lane & 15);
        const int col = kc * 32 + ((lane >> 4) & 3) * 8 + j;
        wthp[i] = (f16)(wth[row * CC + col] * L2E);
        wphp[i] = (f16)(wph[row * CC + col]);
        wgp [i] = (f16)(wg [row * CC + col]);
    }
    for (int i = t; i < 8192; i += 2048){
        const int j = i & 7, lane = (i >> 3) & 63, kc = (i >> 9) & 1, cs = i >> 10;
        const int row = cs * 16 + (lane & 15);
        const int col = kc * 32 + ((lane >> 4) & 3) * 8 + j;
        wlp[i] = (f16)(wl[row * CB + col]);
    }
}

// ---------------------------------------------------------------------------
// Kernel 1: projections. R24: 512-thread blocks (8 waves), GEMM sections
// split across waves -- proj was a latency-bound serial chain (48 MFMA/wave,
// 3 dependent sections, 2 waves/SIMD). Now:
//   waves 0-3: theta for n-group w&3;  waves 4-7: phi for n-group w&3
//   g: wave w -> cb-group w&3, ns-half w>>2 (disjoint rep cols, split stores)
// Critical path 48 -> 24 MFMA, staging 8 -> 4 iters, 4 waves/SIMD.
// ---------------------------------------------------------------------------
__global__ __launch_bounds__(512) void proj_kernel(
    const float* __restrict__ x, const f16* __restrict__ wthp,
    const f16* __restrict__ wphp, const f16* __restrict__ wgp,
    f16* __restrict__ thetaT, f16* __restrict__ phiT, f16* __restrict__ gbuf)
{
    __shared__ __align__(16) f16 xT[64][136];
    __shared__ __align__(16) f16 rep[8][16 * 72];
    const int b  = blockIdx.x & 7;
    const int n0 = (blockIdx.x >> 3) << 6;
    const int t  = threadIdx.x;

    #pragma unroll
    for (int i = 0; i < 4; i++){
        int v  = t + 512 * i;
        int c  = v >> 4;
        int j0 = (v & 15) << 2;
        const f4v xv = *(const f4v*)&x[((size_t)(b * CC + c)) * NN + n0 + j0];
        #pragma unroll
        for (int jj = 0; jj < 4; jj++) xT[j0 + jj][c] = (f16)xv[jj];
    }
    __syncthreads();

    const int w = t >> 6, lane = t & 63, quad = lane >> 4, l15 = lane & 15;
    const int wq = w & 3, grp = w >> 2;
    const int rrow = lane >> 3, rcol = (lane & 7) * 8;

    h8v bx[4];
    #pragma unroll
    for (int kc = 0; kc < 4; kc++)
        bx[kc] = *(const h8v*)&xT[wq * 16 + l15][kc * 32 + quad * 8];

    // ---- theta (grp==0) / phi (grp==1) for n-group wq ----
    {
        const f16* WP = (grp == 0) ? wthp : wphp;
        f16* OUT      = (grp == 0) ? thetaT : phiT;
        for (int ks = 0; ks < 4; ks++){
            f4v acc = {0.f, 0.f, 0.f, 0.f};
            #pragma unroll
            for (int kc = 0; kc < 4; kc++){
                const h8v af = *(const h8v*)&WP[(ks * 4 + kc) * 512 + lane * 8];
                acc = __builtin_amdgcn_mfma_f32_16x16x32_f16(af, bx[kc], acc, 0, 0, 0);
            }
            h4v pv;
            #pragma unroll
            for (int r = 0; r < 4; r++) pv[r] = (f16)acc[r];
            *(h4v*)&rep[w][l15 * 72 + ks * 16 + quad * 4] = pv;
        }
        #pragma unroll
        for (int j = 0; j < 2; j++){
            const h8v vv = *(const h8v*)&rep[w][(rrow + 8 * j) * 72 + rcol];
            *(h8v*)&OUT[((size_t)(b * NN + n0 + wq * 16 + rrow + 8 * j)) * CB + rcol] = vv;
        }
    }
    __syncthreads();   // g below reuses rep[0..3]; theta reads must complete

    // ---- g: wave w -> cb-group wq, ns-half grp (rep cols disjoint) ----
    h8v bw[4];
    #pragma unroll
    for (int kc = 0; kc < 4; kc++)
        bw[kc] = *(const h8v*)&wgp[(wq * 4 + kc) * 512 + lane * 8];
    #pragma unroll
    for (int ns2 = 0; ns2 < 2; ns2++){
        const int ns = grp * 2 + ns2;
        f4v acc = {0.f, 0.f, 0.f, 0.f};
        #pragma unroll
        for (int kc = 0; kc < 4; kc++){
            const h8v af = *(const h8v*)&xT[ns * 16 + l15][kc * 32 + quad * 8];
            acc = __builtin_amdgcn_mfma_f32_16x16x32_f16(af, bw[kc], acc, 0, 0, 0);
        }
        h4v pv;
        #pragma unroll
        for (int r = 0; r < 4; r++) pv[r] = (f16)acc[r];
        *(h4v*)&rep[wq][l15 * 72 + ns * 16 + quad * 4] = pv;
    }
    __syncthreads();   // both halves of rep[wq] complete
    {
        const int row = rrow + 8 * grp;
        const h8v vv = *(const h8v*)&rep[wq][row * 72 + rcol];
        *(h8v*)&gbuf[((size_t)(b * CB + wq * 16 + row)) * NN + n0 + rcol] = vv;
    }
}

// ---------------------------------------------------------------------------
// Kernel 2: fused attention + final projection + residual (R23, proven).
// P-in-register sigma PV, pre-permuted GG via reg-staged g, 3-deep gl_lds ph,
// counted vmcnt(1), raw barriers, STEPK compile-time slots, shuffle-free
// defer-max.
// ---------------------------------------------------------------------------
__global__ __launch_bounds__(512, 4) void attn_kernel(
    const f16* __restrict__ thetaT, const f16* __restrict__ phiT,
    const f16* __restrict__ gbuf, const f16* __restrict__ wlp,
    const float* __restrict__ x, float* __restrict__ out)
{
    __shared__ __align__(16) char SM[49152];
    f16*   const PH  = (f16*)SM;                // [3][4096]   24576 B
    f16*   const GG  = (f16*)(SM + 24576);      // [3][4096]   24576 B
    // epilogue overlays (staging dead):
    float* const MG  = (float*)SM;              // [4][16][68] 17408 B
    float* const ML  = (float*)(SM + 17408);    // [4][16][2]    512 B
    float* const FO  = (float*)SM;              // [128][68]   34816 B
    f16*   const YY  = (f16*)(SM + 36864);      // [64][72]     9216 B

    const int b  = blockIdx.x & 7;              // batch -> XCD swizzle
    const int q0 = (blockIdx.x >> 3) << 6;
    const int t  = threadIdx.x;
    const int w  = t >> 6;                      // 0..7
    const int lane = t & 63, quad = lane >> 4, l15 = lane & 15;
    const int wq = w & 3;                       // query group
    const int h  = w >> 2;                      // key half of 64-key pair
    const int n0 = q0 + wq * 16;

    // theta fragments (16 queries per wave)
    const size_t trow = ((size_t)(b * NN + n0 + l15)) * CB;
    const h8v a0 = *(const h8v*)&thetaT[trow + quad * 8];
    const h8v a1 = *(const h8v*)&thetaT[trow + 32 + quad * 8];

    // ---- staging (all 512 threads; srow = key/cb row 0..63 of the pair) ----
    const int srow = t >> 3;
    const int skg  = t & 7;
    const f16* pS = phiT + ((size_t)(b * NN + srow)) * CB + (skg ^ (srow & 7)) * 8;
    const f16* pG = gbuf + ((size_t)(b * CB + srow)) * NN + skg * 8;
    // g sigma-store: this thread's 8 keys = skg*8..+7 -> 2 chunks x 4 f16
    const int sgs = (srow >> 1) & 3;
    const int cA  = (2 * (skg & 3)) & 3;
    const int gdA = (skg >> 2) * 2048 + srow * 32 + ((cA      ^ sgs) * 8) + ((skg >> 1) & 1) * 4;
    const int gdB = (skg >> 2) * 2048 + srow * 32 + (((cA | 1) ^ sgs) * 8) + ((skg >> 1) & 1) * 4;

    // read swizzles
    const int so0 = (quad ^ (l15 & 7)) * 8;           // ph b128 chunk
    const int so1 = so0 ^ 32;
    const int gvs = (quad ^ ((l15 >> 1) & 3)) * 8;    // GG sigma b128 chunk

    // precomputed base pointers; all slot/tt selects become imm offsets
    const f16* const PB0 = PH + h * 2048 + l15 * 64 + so0;
    const f16* const PB1 = PH + h * 2048 + l15 * 64 + so1;
    const f16* const GB  = GG + h * 2048 + l15 * 32 + gvs;
    f16* const WA = GG + gdA;
    f16* const WB = GG + gdB;
    f16* const PD = PH + t * 8;

    // ---- prologue: g pairs 0,1 -> regs; ph pairs 0,1 -> slots 0,1 ----
    h8v gA = *(const h8v*)pG;                   // g pair 0
    h8v gB = *(const h8v*)(pG + 64);            // g pair 1
    GLD(pS,                    PD);
    GLD(pS + (size_t)64 * CB,  PD + 4096);
    pG += 128;                                  // -> pair 2
    pS += (size_t)128 * CB;                     // -> pair 2
    {   // write g pair 0 -> slot 0
        h4v lo_, hi_;
        #pragma unroll
        for (int j = 0; j < 4; j++){ lo_[j] = gA[j]; hi_[j] = gA[4 + j]; }
        *(h4v*)&WA[0] = lo_;
        *(h4v*)&WB[0] = hi_;
    }

    float mrun = -1e30f, lrun = 0.f;
    const f4v zf = {0.f, 0.f, 0.f, 0.f};
    f4v o[4];
    #pragma unroll
    for (int tt = 0; tt < 4; tt++) o[tt] = zf;

// STEPK(RC, V1, DO_W, DO_L, gw, gl): compute pair with slot RC (literal);
// write g-next from gw into slot (RC+1)%3; load g(m+2)->gl; GLD ph(m+2)
// into slot (RC+2)%3.
#define STEPK(RC, V1, DO_W, DO_L, gw, gl) do {                              \
    if (V1) WAITV1(); else WAITV0();                                        \
    WAITL0();                                                               \
    __builtin_amdgcn_s_barrier();                                           \
    asm volatile("" ::: "memory");                                          \
    if (DO_W){                                                              \
        h4v lo_, hi_;                                                       \
        _Pragma("unroll")                                                   \
        for (int j = 0; j < 4; j++){ lo_[j] = gw[j]; hi_[j] = gw[4 + j]; }  \
        *(h4v*)&WA[((RC + 1) % 3) * 4096] = lo_;                            \
        *(h4v*)&WB[((RC + 1) % 3) * 4096] = hi_;                            \
    }                                                                       \
    if (DO_L){                                                              \
        gl = *(const h8v*)pG;  pG += 64;                                    \
        __builtin_amdgcn_sched_barrier(0);                                  \
        GLD(pS, PD + ((RC + 2) % 3) * 4096);                                \
        pS += (size_t)64 * CB;                                              \
    }                                                                       \
    f4v s0_, s1_;                                                           \
    __builtin_amdgcn_s_setprio(1);                                          \
    {                                                                       \
        const h8v pb0 = *(const h8v*)(PB0 + RC * 4096);                     \
        const h8v pb1 = *(const h8v*)(PB1 + RC * 4096);                     \
        f4v sv = zf;                                                        \
        sv = __builtin_amdgcn_mfma_f32_16x16x32_f16(pb0, a0, sv, 0, 0, 0);  \
        sv = __builtin_amdgcn_mfma_f32_16x16x32_f16(pb1, a1, sv, 0, 0, 0);  \
        s0_ = sv;                                                           \
        const h8v pb2 = *(const h8v*)(PB0 + RC * 4096 + 1024);              \
        const h8v pb3 = *(const h8v*)(PB1 + RC * 4096 + 1024);              \
        f4v sw = zf;                                                        \
        sw = __builtin_amdgcn_mfma_f32_16x16x32_f16(pb2, a0, sw, 0, 0, 0);  \
        sw = __builtin_amdgcn_mfma_f32_16x16x32_f16(pb3, a1, sw, 0, 0, 0);  \
        s1_ = sw;                                                           \
    }                                                                       \
    __builtin_amdgcn_s_setprio(0);                                          \
    float smax_ = fmaxf(fmaxf(s0_[0], s0_[1]), fmaxf(s0_[2], s0_[3]));      \
    smax_ = fmaxf(smax_, fmaxf(fmaxf(s1_[0], s1_[1]), fmaxf(s1_[2], s1_[3])));\
    if (__any(smax_ - mrun > 8.f)){                                         \
        smax_ = fmaxf(smax_, __shfl_xor(smax_, 16));                        \
        smax_ = fmaxf(smax_, __shfl_xor(smax_, 32));                        \
        const float mn_ = fmaxf(mrun, smax_);                               \
        const float al_ = __builtin_amdgcn_exp2f(mrun - mn_);               \
        mrun = mn_;                                                         \
        lrun *= al_;                                                        \
        _Pragma("unroll")                                                   \
        for (int tt = 0; tt < 4; tt++)                                      \
            _Pragma("unroll")                                               \
            for (int r = 0; r < 4; r++)                                     \
                o[tt][r] *= al_;                                            \
    }                                                                       \
    float lsum_ = 0.f;                                                      \
    h8v pa_;                                                                \
    _Pragma("unroll")                                                       \
    for (int r = 0; r < 4; r++){                                            \
        float p_ = __builtin_amdgcn_exp2f(s0_[r] - mrun);                   \
        lsum_ += p_;  pa_[r] = (f16)p_;                                     \
        float q_ = __builtin_amdgcn_exp2f(s1_[r] - mrun);                   \
        lsum_ += q_;  pa_[4 + r] = (f16)q_;                                 \
    }                                                                       \
    lrun += lsum_;                                                          \
    __builtin_amdgcn_s_setprio(1);                                          \
    o[0] = __builtin_amdgcn_mfma_f32_16x16x32_f16(                          \
        *(const h8v*)(GB + RC * 4096 +    0), pa_, o[0], 0, 0, 0);          \
    o[1] = __builtin_amdgcn_mfma_f32_16x16x32_f16(                          \
        *(const h8v*)(GB + RC * 4096 +  512), pa_, o[1], 0, 0, 0);          \
    o[2] = __builtin_amdgcn_mfma_f32_16x16x32_f16(                          \
        *(const h8v*)(GB + RC * 4096 + 1024), pa_, o[2], 0, 0, 0);          \
    o[3] = __builtin_amdgcn_mfma_f32_16x16x32_f16(                          \
        *(const h8v*)(GB + RC * 4096 + 1536), pa_, o[3], 0, 0, 0);          \
    __builtin_amdgcn_s_setprio(0);                                          \
} while (0)

    // m = 0..59 (all full steps): 10 x 6-unrolled
    for (int mm = 0; mm < 60; mm += 6){
        STEPK(0, 1, 1, 1, gB, gA);
        STEPK(1, 1, 1, 1, gA, gB);
        STEPK(2, 1, 1, 1, gB, gA);
        STEPK(0, 1, 1, 1, gA, gB);
        STEPK(1, 1, 1, 1, gB, gA);
        STEPK(2, 1, 1, 1, gA, gB);
    }
    STEPK(0, 1, 1, 1, gB, gA);   // m=60: stage pair 62 -> gA
    STEPK(1, 1, 1, 1, gA, gB);   // m=61: stage pair 63 -> gB
    STEPK(2, 1, 1, 0, gB, gA);   // m=62: write g(63)=gB, no loads
    STEPK(0, 0, 0, 0, gA, gB);   // m=63: drain, compute only
#undef STEPK

    // per-wave l reduce across quads (full l for this wave's key half)
    lrun += __shfl_xor(lrun, 16);
    lrun += __shfl_xor(lrun, 32);

    __syncthreads();   // K-loop done; staging region dead -> merge overlay

    if (h == 1){       // odd-half waves publish (m, l, O)
        #pragma unroll
        for (int tt2 = 0; tt2 < 4; tt2++)
            *(f4v*)&MG[wq * 1088 + l15 * 68 + tt2 * 16 + quad * 4] = o[tt2];
        if (lane < 16){
            ML[wq * 32 + lane * 2 + 0] = mrun;
            ML[wq * 32 + lane * 2 + 1] = lrun;
        }
    }
    __syncthreads();

    if (h == 0){       // even-half waves merge + normalize -> y (f16)
        const float m4 = ML[wq * 32 + l15 * 2 + 0];
        const float l4 = ML[wq * 32 + l15 * 2 + 1];
        const float M  = fmaxf(mrun, m4);
        const float e0 = __builtin_amdgcn_exp2f(mrun - M);
        const float e1 = __builtin_amdgcn_exp2f(m4 - M);
        const float inv = 1.0f / (lrun * e0 + l4 * e1);
        #pragma unroll
        for (int tt2 = 0; tt2 < 4; tt2++){
            const f4v o4 = *(const f4v*)&MG[wq * 1088 + l15 * 68 + tt2 * 16 + quad * 4];
            h4v yv;
            #pragma unroll
            for (int r = 0; r < 4; r++)
                yv[r] = (f16)((o[tt2][r] * e0 + o4[r] * e1) * inv);
            *(h4v*)&YY[(wq * 16 + l15) * 72 + tt2 * 16 + quad * 4] = yv;
        }
    }
    __syncthreads();

    // ---- out-GEMM: D[c][q] = wl(A) * y(B); 8 waves, 4 cs each ----
    const f4v zf2 = {0.f, 0.f, 0.f, 0.f};
    const h8v yB0 = *(const h8v*)&YY[(wq * 16 + l15) * 72 + quad * 8];
    const h8v yB1 = *(const h8v*)&YY[(wq * 16 + l15) * 72 + 32 + quad * 8];
    #pragma unroll
    for (int ci = 0; ci < 4; ci++){
        const int cs = h * 4 + ci;
        const h8v wa0 = *(const h8v*)&wlp[(cs * 2 + 0) * 512 + lane * 8];
        const h8v wa1 = *(const h8v*)&wlp[(cs * 2 + 1) * 512 + lane * 8];
        f4v acc = zf2;
        acc = __builtin_amdgcn_mfma_f32_16x16x32_f16(wa0, yB0, acc, 0, 0, 0);
        acc = __builtin_amdgcn_mfma_f32_16x16x32_f16(wa1, yB1, acc, 0, 0, 0);
        #pragma unroll
        for (int r = 0; r < 4; r++)
            FO[(cs * 16 + quad * 4 + r) * 68 + wq * 16 + l15] = acc[r];
    }
    __syncthreads();

    // ---- residual RMW: fully coalesced float4, 512 threads ----
    #pragma unroll
    for (int i = 0; i < 4; i++){
        const int row = i * 32 + (t >> 4);
        const int nf  = (t & 15) * 4;
        const f4v v = *(const f4v*)&FO[row * 68 + nf];
        const size_t idx = ((size_t)(b * CC + row)) * NN + q0 + nf;
        const f4v xv = *(const f4v*)&x[idx];
        f4v ov;
        #pragma unroll
        for (int r = 0; r < 4; r++) ov[r] = v[r] + xv[r];
        *(f4v*)&out[idx] = ov;
    }
}

extern "C" void kernel_launch(void* const* d_in, const int* in_sizes, int n_in,
                              void* d_out, int out_size, void* d_ws, size_t ws_size,
                              hipStream_t stream)
{
    const float* x   = (const float*)d_in[0];
    const float* wth = (const float*)d_in[1];
    const float* wph = (const float*)d_in[2];
    const float* wg  = (const float*)d_in[3];
    const float* wl  = (const float*)d_in[4];
    float* out = (float*)d_out;

    f16* thetaT = (f16*)d_ws;
    f16* phiT   = thetaT + (size_t)NB * NN * CB;
    f16* gbuf   = phiT   + (size_t)NB * NN * CB;
    f16* wthp   = gbuf   + (size_t)NB * NN * CB;
    f16* wphp   = wthp + 8192;
    f16* wgp    = wphp + 8192;
    f16* wlp    = wgp  + 8192;

    pack_w<<<8, 256, 0, stream>>>(wth, wph, wg, wl, wthp, wphp, wgp, wlp);
    proj_kernel<<<NB * 64, 512, 0, stream>>>(x, wthp, wphp, wgp, thetaT, phiT, gbuf);
    attn_kernel<<<NB * 64, 512, 0, stream>>>(thetaT, phiT, gbuf, wlp, x, out);
}